// Round 2
// baseline (334.420 us; speedup 1.0000x reference)
//
#include <hip/hip_runtime.h>
#include <stdint.h>

#define HH 16
#define DHD 64
#define BB 2
#define NN 2048
#define DD 1024
#define MMOD 4
#define LMAX 256
#define BNROWS (BB*NN)      // 4096
#define QKVN (3*HH*DHD)     // 3072

typedef __attribute__((ext_vector_type(4))) float f32x4;
typedef __attribute__((ext_vector_type(8))) short s16x8;

__device__ __forceinline__ float bf2f(unsigned short b) {
  return __uint_as_float(((unsigned int)b) << 16);
}
__device__ __forceinline__ unsigned short f2bf(float f) {
  unsigned int u = __float_as_uint(f);
  u += 0x7fffu + ((u >> 16) & 1u);
  return (unsigned short)(u >> 16);
}

#define ASYNC_LDS16(g, l) \
  __builtin_amdgcn_global_load_lds((const __attribute__((address_space(1))) void*)(g), \
                                   (__attribute__((address_space(3))) void*)(l), 16, 0, 0)

// ---------------------------------------------------------------------------
// K1: modality splice + norm + gamma, write xn bf16 [4096][1024]
// ---------------------------------------------------------------------------
__global__ __launch_bounds__(256) void k_prep(const float* __restrict__ x,
                                              const float* __restrict__ tokens,
                                              const float* __restrict__ gamma,
                                              const int* __restrict__ mods,
                                              unsigned short* __restrict__ xn) {
  int bs = blockIdx.x;
  int bb = bs / NN, s = bs % NN;
  int t = threadIdx.x;
  int c = t * 4;
  const float4 xv = *(const float4*)(x + (size_t)bs * DD + c);
  float4 acc = {0.f, 0.f, 0.f, 0.f};
  bool any = false;
  #pragma unroll
  for (int m = 0; m < MMOD; ++m) {
    int off = mods[(bb * MMOD + m) * 3 + 1];
    int ln  = mods[(bb * MMOD + m) * 3 + 2];
    if (s >= off && s < off + ln) {
      any = true;
      int rel = s - off;
      if (rel > LMAX - 1) rel = LMAX - 1;
      if (rel < 0) rel = 0;
      const float4 tv = *(const float4*)(tokens + ((size_t)(bb * MMOD + m) * LMAX + rel) * DD + c);
      acc.x += tv.x; acc.y += tv.y; acc.z += tv.z; acc.w += tv.w;
    }
  }
  float4 v = any ? acc : xv;
  float ss = v.x*v.x + v.y*v.y + v.z*v.z + v.w*v.w;
  #pragma unroll
  for (int o = 32; o; o >>= 1) ss += __shfl_xor(ss, o);
  __shared__ float red[4];
  int wv = t >> 6;
  if ((t & 63) == 0) red[wv] = ss;
  __syncthreads();
  float tot = red[0] + red[1] + red[2] + red[3];
  float norm = sqrtf(tot);
  norm = fmaxf(norm, 1e-12f);
  float sc = 32.0f / norm;   // sqrt(1024) = 32
  const float4 g = *(const float4*)(gamma + c);
  unsigned long long pk =
      (unsigned long long)f2bf(v.x * sc * (g.x + 1.f)) |
      ((unsigned long long)f2bf(v.y * sc * (g.y + 1.f)) << 16) |
      ((unsigned long long)f2bf(v.z * sc * (g.z + 1.f)) << 32) |
      ((unsigned long long)f2bf(v.w * sc * (g.w + 1.f)) << 48);
  *(unsigned long long*)(xn + (size_t)bs * DD + c) = pk;
}

// ---------------------------------------------------------------------------
// K2: pos[b][n] = s - cumsum(rot_any). One wave per batch.
// ---------------------------------------------------------------------------
__global__ void k_pos(const int* __restrict__ mods, int* __restrict__ pos) {
  int bb = blockIdx.x;
  int lane = threadIdx.x;       // 64
  int offs[MMOD], ends[MMOD];
  #pragma unroll
  for (int m = 0; m < MMOD; ++m) {
    int off = mods[(bb * MMOD + m) * 3 + 1];
    int ln  = mods[(bb * MMOD + m) * 3 + 2];
    offs[m] = off + 1;
    ends[m] = off + ln;
  }
  int base = lane * (NN / 64);  // 32 per lane
  int lc[NN / 64];
  int tot = 0;
  #pragma unroll
  for (int i = 0; i < NN / 64; ++i) {
    int s = base + i;
    int f = 0;
    #pragma unroll
    for (int m = 0; m < MMOD; ++m)
      if (s >= offs[m] && s < ends[m]) f = 1;
    tot += f;
    lc[i] = tot;
  }
  int v = tot;
  #pragma unroll
  for (int o = 1; o < 64; o <<= 1) {
    int u = __shfl_up(v, o);
    if (lane >= o) v += u;
  }
  int excl = v - tot;
  #pragma unroll
  for (int i = 0; i < NN / 64; ++i)
    pos[bb * NN + base + i] = base + i - (excl + lc[i]);
}

// ---------------------------------------------------------------------------
// K2b: RoPE cos/sin table [b*n][32] float2
// ---------------------------------------------------------------------------
__global__ void k_tab(const int* __restrict__ pos, float2* __restrict__ tab) {
  int gid = blockIdx.x * 256 + threadIdx.x;   // b*n*32 = 131072
  int p = gid & 31;
  int bs = gid >> 5;
  float inv = expf(-((float)p / 32.f) * 9.210340371976184f); // 1/10000^(2p/64)
  float ang = (float)pos[bs] * inv;
  float sn, cs;
  sincosf(ang, &sn, &cs);
  tab[gid] = make_float2(cs, sn);
}

// ---------------------------------------------------------------------------
// K3: transpose f32 [R][C] -> bf16 [C][R]
// ---------------------------------------------------------------------------
__global__ void k_tr(const float* __restrict__ in, unsigned short* __restrict__ out,
                     int R, int C) {
  __shared__ float tile[32][33];
  int bx = blockIdx.x, by = blockIdx.y;
  int tx = threadIdx.x, ty = threadIdx.y;
  #pragma unroll
  for (int k = 0; k < 4; ++k) {
    int r = by * 32 + ty + k * 8, c = bx * 32 + tx;
    tile[ty + k * 8][tx] = in[(size_t)r * C + c];
  }
  __syncthreads();
  #pragma unroll
  for (int k = 0; k < 4; ++k) {
    int oc = bx * 32 + ty + k * 8;
    int orr = by * 32 + tx;
    out[(size_t)oc * R + orr] = f2bf(tile[tx][ty + k * 8]);
  }
}

// ---------------------------------------------------------------------------
// K4/K7: GEMM  C[M][Nn] = A[M][K](bf16) * Bt[Nn][K](bf16)^T
// 128x128 tile, BK=64, 4 waves (2x2), 16x16x32 MFMA, global_load_lds staging.
// ---------------------------------------------------------------------------
template<bool F32OUT>
__global__ __launch_bounds__(256) void k_gemm(const unsigned short* __restrict__ A,
                                              const unsigned short* __restrict__ Bt,
                                              void* __restrict__ Cp,
                                              int M, int Nn, int K) {
  __shared__ unsigned short As[128 * 64];
  __shared__ unsigned short Bs[128 * 64];
  int tid = threadIdx.x;
  int lane = tid & 63, wv = tid >> 6;
  int m0 = blockIdx.y * 128, n0 = blockIdx.x * 128;
  int wr = wv >> 1, wc = wv & 1;
  f32x4 acc[4][4] = {};

  for (int kt = 0; kt < K; kt += 64) {
    __syncthreads();
    #pragma unroll
    for (int is = 0; is < 4; ++is) {
      int li = is * 256 + tid;
      int r = li >> 3, cc = (li & 7) * 8;
      const unsigned short* ga = A  + (size_t)(m0 + r) * K + kt + cc;
      const unsigned short* gb = Bt + (size_t)(n0 + r) * K + kt + cc;
      unsigned short* la = &As[(is * 256 + wv * 64) * 8];
      unsigned short* lb = &Bs[(is * 256 + wv * 64) * 8];
      ASYNC_LDS16(ga, la);
      ASYNC_LDS16(gb, lb);
    }
    __syncthreads();
    #pragma unroll
    for (int ks = 0; ks < 2; ++ks) {
      int ko = ks * 32 + ((lane >> 4) * 8);
      s16x8 af[4], bfr[4];
      #pragma unroll
      for (int m = 0; m < 4; ++m)
        af[m] = *(const s16x8*)&As[(wr * 64 + m * 16 + (lane & 15)) * 64 + ko];
      #pragma unroll
      for (int nn = 0; nn < 4; ++nn)
        bfr[nn] = *(const s16x8*)&Bs[(wc * 64 + nn * 16 + (lane & 15)) * 64 + ko];
      #pragma unroll
      for (int m = 0; m < 4; ++m)
        #pragma unroll
        for (int nn = 0; nn < 4; ++nn)
          acc[m][nn] = __builtin_amdgcn_mfma_f32_16x16x32_bf16(af[m], bfr[nn], acc[m][nn], 0, 0, 0);
    }
  }

  #pragma unroll
  for (int m = 0; m < 4; ++m) {
    #pragma unroll
    for (int nn = 0; nn < 4; ++nn) {
      int r0 = m0 + wr * 64 + m * 16 + ((lane >> 4) * 4);
      int cc = n0 + wc * 64 + nn * 16 + (lane & 15);
      #pragma unroll
      for (int j = 0; j < 4; ++j) {
        float val = acc[m][nn][j];
        if (F32OUT) ((float*)Cp)[(size_t)(r0 + j) * Nn + cc] = val;
        else        ((unsigned short*)Cp)[(size_t)(r0 + j) * Nn + cc] = f2bf(val);
      }
    }
  }
}

// ---------------------------------------------------------------------------
// K5: RoPE apply + reshape qkv_tmp[4096][3072] -> q/k [b*H][n][64] bf16
// q additionally scaled by 1/sqrt(64)=0.125 (folded attention scale)
// ---------------------------------------------------------------------------
__global__ __launch_bounds__(256) void k_rope(const unsigned short* __restrict__ qkv,
                                              const float2* __restrict__ tab,
                                              unsigned short* __restrict__ q,
                                              unsigned short* __restrict__ k) {
  int bs = blockIdx.x;
  int bb = bs / NN, s = bs % NN;
  int lane = threadIdx.x & 63, wv = threadIdx.x >> 6;
  #pragma unroll
  for (int g = wv; g < 32; g += 4) {
    int i3 = g >> 4, h = g & 15;
    float val = bf2f(qkv[(size_t)bs * QKVN + g * 64 + lane]);
    float partner = __shfl_xor(val, 1);
    float2 cs = tab[(size_t)bs * 32 + (lane >> 1)];
    float out;
    if ((lane & 1) == 0) out = val * cs.x - partner * cs.y;      // t1*cos - t2*sin
    else                 out = partner * cs.y + val * cs.x;      // t1*sin + t2*cos
    if (i3 == 0) out *= 0.125f;
    unsigned short* dst = (i3 == 0) ? q : k;
    dst[((size_t)(bb * HH + h) * NN + s) * 64 + lane] = f2bf(out);
  }
}

// ---------------------------------------------------------------------------
// K5b: V transpose: qkvt[.][2048+h*64+dh] -> vT[bh][dh][s]  (bf16)
// ---------------------------------------------------------------------------
__global__ __launch_bounds__(256) void k_vtr(const unsigned short* __restrict__ qkvt,
                                             unsigned short* __restrict__ vT) {
  __shared__ unsigned short t[64][72];
  int s0 = blockIdx.x * 64, bh = blockIdx.y, bb = bh >> 4, h = bh & 15;
  int tid = threadIdx.x;
  int r = tid >> 2, c0 = (tid & 3) * 16;
  int cw = c0 ^ (((r >> 4) & 3) << 4);            // XOR-swizzle bits 4-5 by row>>4
  const unsigned short* src = qkvt + (size_t)(bb * NN + s0 + r) * QKVN + 2048 + h * 64 + c0;
  *(s16x8*)&t[r][cw]     = *(const s16x8*)src;
  *(s16x8*)&t[r][cw + 8] = *(const s16x8*)(src + 8);
  __syncthreads();
  int dh = tid >> 2, sc = (tid & 3) * 16;
  int col2 = dh ^ ((tid & 3) << 4);               // f(row) = ((row>>4)&3)<<4, row=sc+i has row>>4 == tid&3
  s16x8 o1, o2;
  #pragma unroll
  for (int i = 0; i < 8; ++i) {
    o1[i] = (short)t[sc + i][col2];
    o2[i] = (short)t[sc + 8 + i][col2];
  }
  unsigned short* dst = vT + ((size_t)bh * 64 + dh) * NN + s0 + sc;
  *(s16x8*)dst       = o1;
  *(s16x8*)(dst + 8) = o2;
}

// ---------------------------------------------------------------------------
// K6: flash attention, barrier-free: 4 independent waves x 16 q-rows,
// per-wave kv limit, V^T read from global, P via per-wave LDS.
// ---------------------------------------------------------------------------
__global__ __launch_bounds__(256) void k_attn(const unsigned short* __restrict__ q,
                                              const unsigned short* __restrict__ k,
                                              const unsigned short* __restrict__ vT,
                                              const int* __restrict__ mods,
                                              unsigned short* __restrict__ o) {
  __shared__ unsigned short Pw[4][16][72];
  int tid = threadIdx.x;
  int lane = tid & 63, wv = tid >> 6;
  int bh = blockIdx.y;
  int bb = bh >> 4;
  int q0 = ((int)gridDim.x - 1 - (int)blockIdx.x) * 64;   // longest-first
  int q0w = q0 + wv * 16;
  const unsigned short* qb = q + (size_t)bh * NN * 64;
  const unsigned short* kb = k + (size_t)bh * NN * 64;
  const unsigned short* vb = vT + (size_t)bh * 64 * NN;

  s16x8 qf[2];
  {
    int qrow = q0w + (lane & 15);
    #pragma unroll
    for (int ks = 0; ks < 2; ++ks)
      qf[ks] = *(const s16x8*)&qb[(size_t)qrow * 64 + ks * 32 + ((lane >> 4) * 8)];
  }

  int off_[MMOD], end_[MMOD];
  #pragma unroll
  for (int m = 0; m < MMOD; ++m) {
    off_[m] = mods[(bb * MMOD + m) * 3 + 1];
    end_[m] = off_[m] + mods[(bb * MMOD + m) * 3 + 2];
  }
  int limit[4];
  #pragma unroll
  for (int j = 0; j < 4; ++j) {
    int r = q0w + ((lane >> 4) * 4) + j;
    int L = r + 1;
    #pragma unroll
    for (int m = 0; m < MMOD; ++m)
      if (off_[m] <= r && end_[m] > L) L = end_[m];
    limit[j] = L;
  }
  int minlim, kvmax;
  {
    int L = q0w + 1;
    #pragma unroll
    for (int m = 0; m < MMOD; ++m)
      if (off_[m] <= q0w && end_[m] > L) L = end_[m];
    minlim = L;
    int r = q0w + 15;
    int L2 = r + 1;
    #pragma unroll
    for (int m = 0; m < MMOD; ++m)
      if (off_[m] <= r && end_[m] > L2) L2 = end_[m];
    kvmax = L2;
  }

  float mrun[4] = {-1e30f, -1e30f, -1e30f, -1e30f};
  float lrun[4] = {0.f, 0.f, 0.f, 0.f};
  f32x4 accO[4] = {};

  for (int kv0 = 0; kv0 < kvmax; kv0 += 64) {
    // S = Q K^T (q pre-scaled by 0.125)
    f32x4 sv[4];
    #pragma unroll
    for (int cb = 0; cb < 4; ++cb) {
      size_t krow = (size_t)(kv0 + cb * 16 + (lane & 15)) * 64 + ((lane >> 4) * 8);
      s16x8 kf0 = *(const s16x8*)&kb[krow];
      s16x8 kf1 = *(const s16x8*)&kb[krow + 32];
      f32x4 z = {};
      z = __builtin_amdgcn_mfma_f32_16x16x32_bf16(qf[0], kf0, z, 0, 0, 0);
      z = __builtin_amdgcn_mfma_f32_16x16x32_bf16(qf[1], kf1, z, 0, 0, 0);
      sv[cb] = z;
    }

    // softcap: 50*tanh(s/50) = 50 - 100/(exp(s*0.04)+1)  (saturates cleanly)
    bool edge = (kv0 + 64 > minlim);
    float pm[4][4];
    float tmax[4] = {-1e30f, -1e30f, -1e30f, -1e30f};
    #pragma unroll
    for (int cb = 0; cb < 4; ++cb) {
      int col = kv0 + cb * 16 + (lane & 15);
      #pragma unroll
      for (int j = 0; j < 4; ++j) {
        float e2 = __expf(sv[cb][j] * 0.04f);
        float val = 50.f - 100.f * __builtin_amdgcn_rcpf(e2 + 1.f);
        if (edge && col >= limit[j]) val = -1e30f;
        pm[cb][j] = val;
        tmax[j] = fmaxf(tmax[j], val);
      }
    }
    #pragma unroll
    for (int o2 = 1; o2 < 16; o2 <<= 1)
      #pragma unroll
      for (int j = 0; j < 4; ++j)
        tmax[j] = fmaxf(tmax[j], __shfl_xor(tmax[j], o2));

    int need = (tmax[0] > mrun[0]) | (tmax[1] > mrun[1]) |
               (tmax[2] > mrun[2]) | (tmax[3] > mrun[3]);
    if (__any(need)) {
      #pragma unroll
      for (int j = 0; j < 4; ++j) {
        float mn = fmaxf(mrun[j], tmax[j]);
        float corr = __expf(mrun[j] - mn);
        mrun[j] = mn;
        lrun[j] *= corr;
        #pragma unroll
        for (int cb = 0; cb < 4; ++cb) accO[cb][j] *= corr;
      }
    }

    float rsum[4] = {0.f, 0.f, 0.f, 0.f};
    #pragma unroll
    for (int cb = 0; cb < 4; ++cb)
      #pragma unroll
      for (int j = 0; j < 4; ++j) {
        float p = __expf(pm[cb][j] - mrun[j]);
        pm[cb][j] = p;
        rsum[j] += p;
      }
    #pragma unroll
    for (int o2 = 1; o2 < 16; o2 <<= 1)
      #pragma unroll
      for (int j = 0; j < 4; ++j) rsum[j] += __shfl_xor(rsum[j], o2);
    #pragma unroll
    for (int j = 0; j < 4; ++j) lrun[j] += rsum[j];

    // P -> per-wave LDS (within-wave ordering, no barrier needed)
    #pragma unroll
    for (int cb = 0; cb < 4; ++cb)
      #pragma unroll
      for (int j = 0; j < 4; ++j)
        Pw[wv][((lane >> 4) * 4) + j][cb * 16 + (lane & 15)] = f2bf(pm[cb][j]);

    // PV: V^T fragments straight from global (contiguous 16B per lane)
    #pragma unroll
    for (int ks = 0; ks < 2; ++ks) {
      s16x8 pa = *(const s16x8*)&Pw[wv][lane & 15][ks * 32 + ((lane >> 4) * 8)];
      #pragma unroll
      for (int cb = 0; cb < 4; ++cb) {
        const unsigned short* vp =
            &vb[(size_t)(cb * 16 + (lane & 15)) * NN + kv0 + ks * 32 + ((lane >> 4) * 8)];
        s16x8 vf = *(const s16x8*)vp;
        accO[cb] = __builtin_amdgcn_mfma_f32_16x16x32_bf16(pa, vf, accO[cb], 0, 0, 0);
      }
    }
  }

  int h = bh & 15;
  float rl[4];
  #pragma unroll
  for (int j = 0; j < 4; ++j) rl[j] = __builtin_amdgcn_rcpf(lrun[j]);
  #pragma unroll
  for (int cb = 0; cb < 4; ++cb)
    #pragma unroll
    for (int j = 0; j < 4; ++j) {
      int r = q0w + ((lane >> 4) * 4) + j;
      float val = accO[cb][j] * rl[j];
      o[((size_t)(bb * NN) + r) * (HH * DHD) + h * 64 + cb * 16 + (lane & 15)] = f2bf(val);
    }
}

// ---------------------------------------------------------------------------
extern "C" void kernel_launch(void* const* d_in, const int* in_sizes, int n_in,
                              void* d_out, int out_size, void* d_ws, size_t ws_size,
                              hipStream_t stream) {
  (void)in_sizes; (void)n_in; (void)out_size; (void)ws_size;
  const float* x      = (const float*)d_in[0];
  const float* tokens = (const float*)d_in[1];
  const float* gamma  = (const float*)d_in[2];
  const float* w_qkv  = (const float*)d_in[3];
  const float* w_out  = (const float*)d_in[4];
  const int*   mods   = (const int*)d_in[5];

  char* ws = (char*)d_ws;
  unsigned short* xn    = (unsigned short*)(ws + 0);           //  8 MB
  unsigned short* wqkvT = (unsigned short*)(ws + 8388608);     //  6 MB
  unsigned short* woutT = (unsigned short*)(ws + 14680064);    //  2 MB
  unsigned short* qkvt  = (unsigned short*)(ws + 16777216);    // 24 MB
  unsigned short* qd    = (unsigned short*)(ws + 41943040);    //  8 MB
  unsigned short* kd    = (unsigned short*)(ws + 50331648);    //  8 MB
  unsigned short* vTd   = (unsigned short*)(ws + 58720256);    //  8 MB
  unsigned short* attno = (unsigned short*)(ws + 67108864);    //  8 MB
  int*            pos   = (int*)(ws + 75497472);               // 16 KB
  float2*         tab   = (float2*)(ws + 75513856);            //  1 MB

  k_prep<<<BNROWS, 256, 0, stream>>>(x, tokens, gamma, mods, xn);
  k_pos<<<BB, 64, 0, stream>>>(mods, pos);
  k_tab<<<(BB * NN * 32) / 256, 256, 0, stream>>>(pos, tab);
  k_tr<<<dim3(QKVN / 32, DD / 32), dim3(32, 8), 0, stream>>>(w_qkv, wqkvT, DD, QKVN);
  k_tr<<<dim3((HH * DHD) / 32, DD / 32), dim3(32, 8), 0, stream>>>(w_out, woutT, HH * DHD, DD);
  k_gemm<false><<<dim3(QKVN / 128, BNROWS / 128), 256, 0, stream>>>(xn, wqkvT, (void*)qkvt, BNROWS, QKVN, DD);
  k_rope<<<BNROWS, 256, 0, stream>>>(qkvt, tab, qd, kd);
  k_vtr<<<dim3(NN / 64, BB * HH), 256, 0, stream>>>(qkvt, vTd);
  k_attn<<<dim3(NN / 64, BB * HH), 256, 0, stream>>>(qd, kd, vTd, mods, attno);
  k_gemm<true><<<dim3(DD / 128, BNROWS / 128), 256, 0, stream>>>(attno, woutT, d_out, BNROWS, DD, DD);
}

// Round 3
// 181.944 us; speedup vs baseline: 1.8380x; 1.8380x over previous
//
#include <hip/hip_runtime.h>
#include <stdint.h>

#define HH 16
#define DHD 64
#define BB 2
#define NN 2048
#define DD 1024
#define MMOD 4
#define LMAX 256
#define BNROWS (BB*NN)      // 4096
#define QKVN (3*HH*DHD)     // 3072

typedef __attribute__((ext_vector_type(4))) float f32x4;
typedef __attribute__((ext_vector_type(8))) short s16x8;

__device__ __forceinline__ float bf2f(unsigned short b) {
  return __uint_as_float(((unsigned int)b) << 16);
}
__device__ __forceinline__ unsigned short f2bf(float f) {
  unsigned int u = __float_as_uint(f);
  u += 0x7fffu + ((u >> 16) & 1u);
  return (unsigned short)(u >> 16);
}

#define ASYNC_LDS16(g, l) \
  __builtin_amdgcn_global_load_lds((const __attribute__((address_space(1))) void*)(g), \
                                   (__attribute__((address_space(3))) void*)(l), 16, 0, 0)

// ---------------------------------------------------------------------------
// K1: modality splice + norm + gamma, write xn bf16 [4096][1024]
// ---------------------------------------------------------------------------
__global__ __launch_bounds__(256) void k_prep(const float* __restrict__ x,
                                              const float* __restrict__ tokens,
                                              const float* __restrict__ gamma,
                                              const int* __restrict__ mods,
                                              unsigned short* __restrict__ xn) {
  int bs = blockIdx.x;
  int bb = bs / NN, s = bs % NN;
  int t = threadIdx.x;
  int c = t * 4;
  const float4 xv = *(const float4*)(x + (size_t)bs * DD + c);
  float4 acc = {0.f, 0.f, 0.f, 0.f};
  bool any = false;
  #pragma unroll
  for (int m = 0; m < MMOD; ++m) {
    int off = mods[(bb * MMOD + m) * 3 + 1];
    int ln  = mods[(bb * MMOD + m) * 3 + 2];
    if (s >= off && s < off + ln) {
      any = true;
      int rel = s - off;
      if (rel > LMAX - 1) rel = LMAX - 1;
      if (rel < 0) rel = 0;
      const float4 tv = *(const float4*)(tokens + ((size_t)(bb * MMOD + m) * LMAX + rel) * DD + c);
      acc.x += tv.x; acc.y += tv.y; acc.z += tv.z; acc.w += tv.w;
    }
  }
  float4 v = any ? acc : xv;
  float ss = v.x*v.x + v.y*v.y + v.z*v.z + v.w*v.w;
  #pragma unroll
  for (int o = 32; o; o >>= 1) ss += __shfl_xor(ss, o);
  __shared__ float red[4];
  int wv = t >> 6;
  if ((t & 63) == 0) red[wv] = ss;
  __syncthreads();
  float tot = red[0] + red[1] + red[2] + red[3];
  float norm = sqrtf(tot);
  norm = fmaxf(norm, 1e-12f);
  float sc = 32.0f / norm;   // sqrt(1024) = 32
  const float4 g = *(const float4*)(gamma + c);
  unsigned long long pk =
      (unsigned long long)f2bf(v.x * sc * (g.x + 1.f)) |
      ((unsigned long long)f2bf(v.y * sc * (g.y + 1.f)) << 16) |
      ((unsigned long long)f2bf(v.z * sc * (g.z + 1.f)) << 32) |
      ((unsigned long long)f2bf(v.w * sc * (g.w + 1.f)) << 48);
  *(unsigned long long*)(xn + (size_t)bs * DD + c) = pk;
}

// ---------------------------------------------------------------------------
// K2: pos[b][n] = s - cumsum(rot_any). One wave per batch.
// ---------------------------------------------------------------------------
__global__ void k_pos(const int* __restrict__ mods, int* __restrict__ pos) {
  int bb = blockIdx.x;
  int lane = threadIdx.x;       // 64
  int offs[MMOD], ends[MMOD];
  #pragma unroll
  for (int m = 0; m < MMOD; ++m) {
    int off = mods[(bb * MMOD + m) * 3 + 1];
    int ln  = mods[(bb * MMOD + m) * 3 + 2];
    offs[m] = off + 1;
    ends[m] = off + ln;
  }
  int base = lane * (NN / 64);  // 32 per lane
  int lc[NN / 64];
  int tot = 0;
  #pragma unroll
  for (int i = 0; i < NN / 64; ++i) {
    int s = base + i;
    int f = 0;
    #pragma unroll
    for (int m = 0; m < MMOD; ++m)
      if (s >= offs[m] && s < ends[m]) f = 1;
    tot += f;
    lc[i] = tot;
  }
  int v = tot;
  #pragma unroll
  for (int o = 1; o < 64; o <<= 1) {
    int u = __shfl_up(v, o);
    if (lane >= o) v += u;
  }
  int excl = v - tot;
  #pragma unroll
  for (int i = 0; i < NN / 64; ++i)
    pos[bb * NN + base + i] = base + i - (excl + lc[i]);
}

// ---------------------------------------------------------------------------
// K2b: RoPE cos/sin table [b*n][32] float2
// ---------------------------------------------------------------------------
__global__ void k_tab(const int* __restrict__ pos, float2* __restrict__ tab) {
  int gid = blockIdx.x * 256 + threadIdx.x;   // b*n*32 = 131072
  int p = gid & 31;
  int bs = gid >> 5;
  float inv = expf(-((float)p / 32.f) * 9.210340371976184f); // 1/10000^(2p/64)
  float ang = (float)pos[bs] * inv;
  float sn, cs;
  sincosf(ang, &sn, &cs);
  tab[gid] = make_float2(cs, sn);
}

// ---------------------------------------------------------------------------
// K3: transpose f32 [R][C] -> bf16 [C][R]
// ---------------------------------------------------------------------------
__global__ void k_tr(const float* __restrict__ in, unsigned short* __restrict__ out,
                     int R, int C) {
  __shared__ float tile[32][33];
  int bx = blockIdx.x, by = blockIdx.y;
  int tx = threadIdx.x, ty = threadIdx.y;
  #pragma unroll
  for (int k = 0; k < 4; ++k) {
    int r = by * 32 + ty + k * 8, c = bx * 32 + tx;
    tile[ty + k * 8][tx] = in[(size_t)r * C + c];
  }
  __syncthreads();
  #pragma unroll
  for (int k = 0; k < 4; ++k) {
    int oc = bx * 32 + ty + k * 8;
    int orr = by * 32 + tx;
    out[(size_t)oc * R + orr] = f2bf(tile[tx][ty + k * 8]);
  }
}

// ---------------------------------------------------------------------------
// K4/K7: GEMM  C[M][Nn] = A[M][K](bf16) * Bt[Nn][K](bf16)^T
// ---------------------------------------------------------------------------
template<bool F32OUT>
__global__ __launch_bounds__(256) void k_gemm(const unsigned short* __restrict__ A,
                                              const unsigned short* __restrict__ Bt,
                                              void* __restrict__ Cp,
                                              int M, int Nn, int K) {
  __shared__ unsigned short As[128 * 64];
  __shared__ unsigned short Bs[128 * 64];
  int tid = threadIdx.x;
  int lane = tid & 63, wv = tid >> 6;
  int m0 = blockIdx.y * 128, n0 = blockIdx.x * 128;
  int wr = wv >> 1, wc = wv & 1;
  f32x4 acc[4][4] = {};

  for (int kt = 0; kt < K; kt += 64) {
    __syncthreads();
    #pragma unroll
    for (int is = 0; is < 4; ++is) {
      int li = is * 256 + tid;
      int r = li >> 3, cc = (li & 7) * 8;
      const unsigned short* ga = A  + (size_t)(m0 + r) * K + kt + cc;
      const unsigned short* gb = Bt + (size_t)(n0 + r) * K + kt + cc;
      unsigned short* la = &As[(is * 256 + wv * 64) * 8];
      unsigned short* lb = &Bs[(is * 256 + wv * 64) * 8];
      ASYNC_LDS16(ga, la);
      ASYNC_LDS16(gb, lb);
    }
    __syncthreads();
    #pragma unroll
    for (int ks = 0; ks < 2; ++ks) {
      int ko = ks * 32 + ((lane >> 4) * 8);
      s16x8 af[4], bfr[4];
      #pragma unroll
      for (int m = 0; m < 4; ++m)
        af[m] = *(const s16x8*)&As[(wr * 64 + m * 16 + (lane & 15)) * 64 + ko];
      #pragma unroll
      for (int nn = 0; nn < 4; ++nn)
        bfr[nn] = *(const s16x8*)&Bs[(wc * 64 + nn * 16 + (lane & 15)) * 64 + ko];
      #pragma unroll
      for (int m = 0; m < 4; ++m)
        #pragma unroll
        for (int nn = 0; nn < 4; ++nn)
          acc[m][nn] = __builtin_amdgcn_mfma_f32_16x16x32_bf16(af[m], bfr[nn], acc[m][nn], 0, 0, 0);
    }
  }

  #pragma unroll
  for (int m = 0; m < 4; ++m) {
    #pragma unroll
    for (int nn = 0; nn < 4; ++nn) {
      int r0 = m0 + wr * 64 + m * 16 + ((lane >> 4) * 4);
      int cc = n0 + wc * 64 + nn * 16 + (lane & 15);
      #pragma unroll
      for (int j = 0; j < 4; ++j) {
        float val = acc[m][nn][j];
        if (F32OUT) ((float*)Cp)[(size_t)(r0 + j) * Nn + cc] = val;
        else        ((unsigned short*)Cp)[(size_t)(r0 + j) * Nn + cc] = f2bf(val);
      }
    }
  }
}

// ---------------------------------------------------------------------------
// K5: RoPE apply + reshape qkv_tmp[4096][3072] -> q/k [b*H][n][64] bf16
// q additionally scaled by 1/sqrt(64)=0.125 (folded attention scale)
// ---------------------------------------------------------------------------
__global__ __launch_bounds__(256) void k_rope(const unsigned short* __restrict__ qkv,
                                              const float2* __restrict__ tab,
                                              unsigned short* __restrict__ q,
                                              unsigned short* __restrict__ k) {
  int bs = blockIdx.x;
  int bb = bs / NN, s = bs % NN;
  int lane = threadIdx.x & 63, wv = threadIdx.x >> 6;
  #pragma unroll
  for (int g = wv; g < 32; g += 4) {
    int i3 = g >> 4, h = g & 15;
    float val = bf2f(qkv[(size_t)bs * QKVN + g * 64 + lane]);
    float partner = __shfl_xor(val, 1);
    float2 cs = tab[(size_t)bs * 32 + (lane >> 1)];
    float out;
    if ((lane & 1) == 0) out = val * cs.x - partner * cs.y;      // t1*cos - t2*sin
    else                 out = partner * cs.y + val * cs.x;      // t1*sin + t2*cos
    if (i3 == 0) out *= 0.125f;
    unsigned short* dst = (i3 == 0) ? q : k;
    dst[((size_t)(bb * HH + h) * NN + s) * 64 + lane] = f2bf(out);
  }
}

// ---------------------------------------------------------------------------
// K5b: V transpose: qkvt[.][2048+h*64+dh] -> vT[bh][dh][s]  (bf16)
// ---------------------------------------------------------------------------
__global__ __launch_bounds__(256) void k_vtr(const unsigned short* __restrict__ qkvt,
                                             unsigned short* __restrict__ vT) {
  __shared__ unsigned short t[64][72];
  int s0 = blockIdx.x * 64, bh = blockIdx.y, bb = bh >> 4, h = bh & 15;
  int tid = threadIdx.x;
  int r = tid >> 2, c0 = (tid & 3) * 16;
  int cw = c0 ^ (((r >> 4) & 3) << 4);
  const unsigned short* src = qkvt + (size_t)(bb * NN + s0 + r) * QKVN + 2048 + h * 64 + c0;
  *(s16x8*)&t[r][cw]     = *(const s16x8*)src;
  *(s16x8*)&t[r][cw + 8] = *(const s16x8*)(src + 8);
  __syncthreads();
  int dh = tid >> 2, sc = (tid & 3) * 16;
  int col2 = dh ^ ((tid & 3) << 4);
  s16x8 o1, o2;
  #pragma unroll
  for (int i = 0; i < 8; ++i) {
    o1[i] = (short)t[sc + i][col2];
    o2[i] = (short)t[sc + 8 + i][col2];
  }
  unsigned short* dst = vT + ((size_t)bh * 64 + dh) * NN + s0 + sc;
  *(s16x8*)dst       = o1;
  *(s16x8*)(dst + 8) = o2;
}

// ---------------------------------------------------------------------------
// K6: flash attention, LDS-staged K/V (double-buffered, XOR-swizzled),
// fixed-max softmax (softcap bounds scores to +-50), no cross-lane ops
// in the inner loop. 4 waves x 16 q-rows per block of 64 q-rows.
// ---------------------------------------------------------------------------
__global__ __launch_bounds__(256) void k_attn(const unsigned short* __restrict__ q,
                                              const unsigned short* __restrict__ k,
                                              const unsigned short* __restrict__ vT,
                                              const int* __restrict__ mods,
                                              unsigned short* __restrict__ o) {
  __shared__ unsigned short Ks[2][64 * 64];
  __shared__ unsigned short Vs[2][64 * 64];
  __shared__ unsigned short Pw[4][16][72];
  int tid = threadIdx.x;
  int lane = tid & 63, wv = tid >> 6;
  int lo = lane & 15, hi = lane >> 4;

  // XCD-aware remap (1024 blocks, 8 XCDs -> 128 contiguous per XCD), then
  // longest-first within each bh.
  int fid = blockIdx.y * gridDim.x + blockIdx.x;      // 0..1023
  int nid = (fid & 7) * 128 + (fid >> 3);
  int bh = nid >> 5;
  int qt = nid & 31;
  int q0 = (31 - qt) * 64;
  int bb = bh >> 4;
  int q0w = q0 + wv * 16;

  const unsigned short* qb = q + (size_t)bh * NN * 64;
  const unsigned short* kb = k + (size_t)bh * NN * 64;
  const unsigned short* vb = vT + (size_t)bh * 64 * NN;

  s16x8 qf[2];
  {
    int qrow = q0w + lo;
    #pragma unroll
    for (int ks = 0; ks < 2; ++ks)
      qf[ks] = *(const s16x8*)&qb[(size_t)qrow * 64 + ks * 32 + hi * 8];
  }

  int off_[MMOD], end_[MMOD];
  #pragma unroll
  for (int m = 0; m < MMOD; ++m) {
    off_[m] = mods[(bb * MMOD + m) * 3 + 1];
    end_[m] = off_[m] + mods[(bb * MMOD + m) * 3 + 2];
  }
  int limit[4];
  #pragma unroll
  for (int j = 0; j < 4; ++j) {
    int r = q0w + hi * 4 + j;
    int L = r + 1;
    #pragma unroll
    for (int m = 0; m < MMOD; ++m)
      if (off_[m] <= r && end_[m] > L) L = end_[m];
    limit[j] = L;
  }
  int minlim, kvmax_w, Lblk;
  {
    int L = q0w + 1;
    #pragma unroll
    for (int m = 0; m < MMOD; ++m)
      if (off_[m] <= q0w && end_[m] > L) L = end_[m];
    minlim = L;
    int r = q0w + 15;
    int L2 = r + 1;
    #pragma unroll
    for (int m = 0; m < MMOD; ++m)
      if (off_[m] <= r && end_[m] > L2) L2 = end_[m];
    kvmax_w = L2;
    int rb = q0 + 63;
    int L3 = rb + 1;
    #pragma unroll
    for (int m = 0; m < MMOD; ++m)
      if (off_[m] <= rb && end_[m] > L3) L3 = end_[m];
    Lblk = L3;
  }
  int nt = (Lblk + 63) >> 6;

  // staging: tile chunk C = (wv*2+i)*64 + lane; row = C>>3, colchunk = C&7,
  // src colchunk = (lane&7) ^ ((lane>>3)&7)  (XOR swizzle, dest stays linear)
  #define STAGE_KV(B, KV0) do { \
    _Pragma("unroll") \
    for (int i_ = 0; i_ < 2; ++i_) { \
      int r_ = (wv * 2 + i_) * 8 + (lane >> 3); \
      int cs_ = (lane & 7) ^ ((lane >> 3) & 7); \
      const unsigned short* gK_ = kb + (size_t)((KV0) + r_) * 64 + cs_ * 8; \
      ASYNC_LDS16(gK_, &Ks[B][(wv * 2 + i_) * 512]); \
      const unsigned short* gV_ = vb + (size_t)r_ * NN + (KV0) + cs_ * 8; \
      ASYNC_LDS16(gV_, &Vs[B][(wv * 2 + i_) * 512]); \
    } \
  } while (0)

  float lrunp[4] = {0.f, 0.f, 0.f, 0.f};
  f32x4 accO[4] = {};

  STAGE_KV(0, 0);
  __syncthreads();
  int buf = 0;
  for (int t = 0; t < nt; ++t) {
    if (t + 1 < nt) STAGE_KV(buf ^ 1, (t + 1) << 6);
    int kv0 = t << 6;
    if (kv0 < kvmax_w) {
      // QK^T from swizzled LDS
      f32x4 sv[4];
      #pragma unroll
      for (int cb = 0; cb < 4; ++cb) {
        int krow = cb * 16 + lo;
        int c0 = (hi) ^ (krow & 7);
        int c1 = (4 + hi) ^ (krow & 7);
        s16x8 kf0 = *(const s16x8*)&Ks[buf][krow * 64 + c0 * 8];
        s16x8 kf1 = *(const s16x8*)&Ks[buf][krow * 64 + c1 * 8];
        f32x4 z = {};
        z = __builtin_amdgcn_mfma_f32_16x16x32_bf16(qf[0], kf0, z, 0, 0, 0);
        z = __builtin_amdgcn_mfma_f32_16x16x32_bf16(qf[1], kf1, z, 0, 0, 0);
        sv[cb] = z;
      }

      // fixed-max softmax: p = exp(cap(s) - 50) = exp(-100/(exp(0.04 s)+1))
      bool edge = (kv0 + 64 > minlim);
      #pragma unroll
      for (int cb = 0; cb < 4; ++cb) {
        int col = kv0 + cb * 16 + lo;
        #pragma unroll
        for (int j = 0; j < 4; ++j) {
          float e2 = __expf(sv[cb][j] * 0.04f);
          float p = __expf(-100.f * __builtin_amdgcn_rcpf(e2 + 1.f));
          if (edge && col >= limit[j]) p = 0.f;
          lrunp[j] += p;
          Pw[wv][hi * 4 + j][cb * 16 + lo] = f2bf(p);
        }
      }

      // PV from swizzled LDS
      #pragma unroll
      for (int ks = 0; ks < 2; ++ks) {
        s16x8 pa = *(const s16x8*)&Pw[wv][lo][ks * 32 + hi * 8];
        #pragma unroll
        for (int cb = 0; cb < 4; ++cb) {
          int vrow = cb * 16 + lo;
          int vc = (ks * 4 + hi) ^ (vrow & 7);
          s16x8 vf = *(const s16x8*)&Vs[buf][vrow * 64 + vc * 8];
          accO[cb] = __builtin_amdgcn_mfma_f32_16x16x32_bf16(pa, vf, accO[cb], 0, 0, 0);
        }
      }
    }
    __syncthreads();
    buf ^= 1;
  }

  // final 16-lane reduce of the per-lane softmax denominators
  #pragma unroll
  for (int o2 = 1; o2 < 16; o2 <<= 1)
    #pragma unroll
    for (int j = 0; j < 4; ++j) lrunp[j] += __shfl_xor(lrunp[j], o2);

  int h = bh & 15;
  float rl[4];
  #pragma unroll
  for (int j = 0; j < 4; ++j) rl[j] = __builtin_amdgcn_rcpf(lrunp[j]);
  #pragma unroll
  for (int cb = 0; cb < 4; ++cb)
    #pragma unroll
    for (int j = 0; j < 4; ++j) {
      int r = q0w + hi * 4 + j;
      float val = accO[cb][j] * rl[j];
      o[((size_t)(bb * NN) + r) * (HH * DHD) + h * 64 + cb * 16 + lo] = f2bf(val);
    }
}

// ---------------------------------------------------------------------------
extern "C" void kernel_launch(void* const* d_in, const int* in_sizes, int n_in,
                              void* d_out, int out_size, void* d_ws, size_t ws_size,
                              hipStream_t stream) {
  (void)in_sizes; (void)n_in; (void)out_size; (void)ws_size;
  const float* x      = (const float*)d_in[0];
  const float* tokens = (const float*)d_in[1];
  const float* gamma  = (const float*)d_in[2];
  const float* w_qkv  = (const float*)d_in[3];
  const float* w_out  = (const float*)d_in[4];
  const int*   mods   = (const int*)d_in[5];

  char* ws = (char*)d_ws;
  unsigned short* xn    = (unsigned short*)(ws + 0);           //  8 MB
  unsigned short* wqkvT = (unsigned short*)(ws + 8388608);     //  6 MB
  unsigned short* woutT = (unsigned short*)(ws + 14680064);    //  2 MB
  unsigned short* qkvt  = (unsigned short*)(ws + 16777216);    // 24 MB
  unsigned short* qd    = (unsigned short*)(ws + 41943040);    //  8 MB
  unsigned short* kd    = (unsigned short*)(ws + 50331648);    //  8 MB
  unsigned short* vTd   = (unsigned short*)(ws + 58720256);    //  8 MB
  unsigned short* attno = (unsigned short*)(ws + 67108864);    //  8 MB
  int*            pos   = (int*)(ws + 75497472);               // 16 KB
  float2*         tab   = (float2*)(ws + 75513856);            //  1 MB

  k_prep<<<BNROWS, 256, 0, stream>>>(x, tokens, gamma, mods, xn);
  k_pos<<<BB, 64, 0, stream>>>(mods, pos);
  k_tab<<<(BB * NN * 32) / 256, 256, 0, stream>>>(pos, tab);
  k_tr<<<dim3(QKVN / 32, DD / 32), dim3(32, 8), 0, stream>>>(w_qkv, wqkvT, DD, QKVN);
  k_tr<<<dim3((HH * DHD) / 32, DD / 32), dim3(32, 8), 0, stream>>>(w_out, woutT, HH * DHD, DD);
  k_gemm<false><<<dim3(QKVN / 128, BNROWS / 128), 256, 0, stream>>>(xn, wqkvT, (void*)qkvt, BNROWS, QKVN, DD);
  k_rope<<<BNROWS, 256, 0, stream>>>(qkvt, tab, qd, kd);
  k_vtr<<<dim3(NN / 64, BB * HH), 256, 0, stream>>>(qkvt, vTd);
  k_attn<<<dim3(NN / 64, BB * HH), 256, 0, stream>>>(qd, kd, vTd, mods, attno);
  k_gemm<true><<<dim3(DD / 128, BNROWS / 128), 256, 0, stream>>>(attno, woutT, d_out, BNROWS, DD, DD);
}

// Round 4
// 166.742 us; speedup vs baseline: 2.0056x; 1.0912x over previous
//
#include <hip/hip_runtime.h>
#include <stdint.h>

#define HH 16
#define DHD 64
#define BB 2
#define NN 2048
#define DD 1024
#define MMOD 4
#define LMAX 256
#define BNROWS (BB*NN)      // 4096
#define QKVN (3*HH*DHD)     // 3072

typedef __attribute__((ext_vector_type(4))) float f32x4;
typedef __attribute__((ext_vector_type(8))) short s16x8;

__device__ __forceinline__ float bf2f(unsigned short b) {
  return __uint_as_float(((unsigned int)b) << 16);
}
__device__ __forceinline__ unsigned short f2bf(float f) {
  unsigned int u = __float_as_uint(f);
  u += 0x7fffu + ((u >> 16) & 1u);
  return (unsigned short)(u >> 16);
}

#define ASYNC_LDS16(g, l) \
  __builtin_amdgcn_global_load_lds((const __attribute__((address_space(1))) void*)(g), \
                                   (__attribute__((address_space(3))) void*)(l), 16, 0, 0)

// ---------------------------------------------------------------------------
// K1: modality splice + norm + gamma, write xn bf16 [4096][1024]
// ---------------------------------------------------------------------------
__global__ __launch_bounds__(256) void k_prep(const float* __restrict__ x,
                                              const float* __restrict__ tokens,
                                              const float* __restrict__ gamma,
                                              const int* __restrict__ mods,
                                              unsigned short* __restrict__ xn) {
  int bs = blockIdx.x;
  int bb = bs / NN, s = bs % NN;
  int t = threadIdx.x;
  int c = t * 4;
  const float4 xv = *(const float4*)(x + (size_t)bs * DD + c);
  float4 acc = {0.f, 0.f, 0.f, 0.f};
  bool any = false;
  #pragma unroll
  for (int m = 0; m < MMOD; ++m) {
    int off = mods[(bb * MMOD + m) * 3 + 1];
    int ln  = mods[(bb * MMOD + m) * 3 + 2];
    if (s >= off && s < off + ln) {
      any = true;
      int rel = s - off;
      if (rel > LMAX - 1) rel = LMAX - 1;
      if (rel < 0) rel = 0;
      const float4 tv = *(const float4*)(tokens + ((size_t)(bb * MMOD + m) * LMAX + rel) * DD + c);
      acc.x += tv.x; acc.y += tv.y; acc.z += tv.z; acc.w += tv.w;
    }
  }
  float4 v = any ? acc : xv;
  float ss = v.x*v.x + v.y*v.y + v.z*v.z + v.w*v.w;
  #pragma unroll
  for (int o = 32; o; o >>= 1) ss += __shfl_xor(ss, o);
  __shared__ float red[4];
  int wv = t >> 6;
  if ((t & 63) == 0) red[wv] = ss;
  __syncthreads();
  float tot = red[0] + red[1] + red[2] + red[3];
  float norm = sqrtf(tot);
  norm = fmaxf(norm, 1e-12f);
  float sc = 32.0f / norm;   // sqrt(1024) = 32
  const float4 g = *(const float4*)(gamma + c);
  unsigned long long pk =
      (unsigned long long)f2bf(v.x * sc * (g.x + 1.f)) |
      ((unsigned long long)f2bf(v.y * sc * (g.y + 1.f)) << 16) |
      ((unsigned long long)f2bf(v.z * sc * (g.z + 1.f)) << 32) |
      ((unsigned long long)f2bf(v.w * sc * (g.w + 1.f)) << 48);
  *(unsigned long long*)(xn + (size_t)bs * DD + c) = pk;
}

// ---------------------------------------------------------------------------
// K2: pos[b][n] = s - cumsum(rot_any). One wave per batch.
// ---------------------------------------------------------------------------
__global__ void k_pos(const int* __restrict__ mods, int* __restrict__ pos) {
  int bb = blockIdx.x;
  int lane = threadIdx.x;       // 64
  int offs[MMOD], ends[MMOD];
  #pragma unroll
  for (int m = 0; m < MMOD; ++m) {
    int off = mods[(bb * MMOD + m) * 3 + 1];
    int ln  = mods[(bb * MMOD + m) * 3 + 2];
    offs[m] = off + 1;
    ends[m] = off + ln;
  }
  int base = lane * (NN / 64);  // 32 per lane
  int lc[NN / 64];
  int tot = 0;
  #pragma unroll
  for (int i = 0; i < NN / 64; ++i) {
    int s = base + i;
    int f = 0;
    #pragma unroll
    for (int m = 0; m < MMOD; ++m)
      if (s >= offs[m] && s < ends[m]) f = 1;
    tot += f;
    lc[i] = tot;
  }
  int v = tot;
  #pragma unroll
  for (int o = 1; o < 64; o <<= 1) {
    int u = __shfl_up(v, o);
    if (lane >= o) v += u;
  }
  int excl = v - tot;
  #pragma unroll
  for (int i = 0; i < NN / 64; ++i)
    pos[bb * NN + base + i] = base + i - (excl + lc[i]);
}

// ---------------------------------------------------------------------------
// K2b: RoPE cos/sin table [b*n][32] float2
// ---------------------------------------------------------------------------
__global__ void k_tab(const int* __restrict__ pos, float2* __restrict__ tab) {
  int gid = blockIdx.x * 256 + threadIdx.x;   // b*n*32 = 131072
  int p = gid & 31;
  int bs = gid >> 5;
  float inv = expf(-((float)p / 32.f) * 9.210340371976184f); // 1/10000^(2p/64)
  float ang = (float)pos[bs] * inv;
  float sn, cs;
  sincosf(ang, &sn, &cs);
  tab[gid] = make_float2(cs, sn);
}

// ---------------------------------------------------------------------------
// K3: transpose f32 [R][C] -> bf16 [C][R]
// ---------------------------------------------------------------------------
__global__ void k_tr(const float* __restrict__ in, unsigned short* __restrict__ out,
                     int R, int C) {
  __shared__ float tile[32][33];
  int bx = blockIdx.x, by = blockIdx.y;
  int tx = threadIdx.x, ty = threadIdx.y;
  #pragma unroll
  for (int k = 0; k < 4; ++k) {
    int r = by * 32 + ty + k * 8, c = bx * 32 + tx;
    tile[ty + k * 8][tx] = in[(size_t)r * C + c];
  }
  __syncthreads();
  #pragma unroll
  for (int k = 0; k < 4; ++k) {
    int oc = bx * 32 + ty + k * 8;
    int orr = by * 32 + tx;
    out[(size_t)oc * R + orr] = f2bf(tile[tx][ty + k * 8]);
  }
}

// ---------------------------------------------------------------------------
// K4/K7: GEMM  C[M][Nn] = A[M][K](bf16) * Bt[Nn][K](bf16)^T
// ---------------------------------------------------------------------------
template<bool F32OUT>
__global__ __launch_bounds__(256) void k_gemm(const unsigned short* __restrict__ A,
                                              const unsigned short* __restrict__ Bt,
                                              void* __restrict__ Cp,
                                              int M, int Nn, int K) {
  __shared__ unsigned short As[128 * 64];
  __shared__ unsigned short Bs[128 * 64];
  int tid = threadIdx.x;
  int lane = tid & 63, wv = tid >> 6;
  int m0 = blockIdx.y * 128, n0 = blockIdx.x * 128;
  int wr = wv >> 1, wc = wv & 1;
  f32x4 acc[4][4] = {};

  for (int kt = 0; kt < K; kt += 64) {
    __syncthreads();
    #pragma unroll
    for (int is = 0; is < 4; ++is) {
      int li = is * 256 + tid;
      int r = li >> 3, cc = (li & 7) * 8;
      const unsigned short* ga = A  + (size_t)(m0 + r) * K + kt + cc;
      const unsigned short* gb = Bt + (size_t)(n0 + r) * K + kt + cc;
      unsigned short* la = &As[(is * 256 + wv * 64) * 8];
      unsigned short* lb = &Bs[(is * 256 + wv * 64) * 8];
      ASYNC_LDS16(ga, la);
      ASYNC_LDS16(gb, lb);
    }
    __syncthreads();
    #pragma unroll
    for (int ks = 0; ks < 2; ++ks) {
      int ko = ks * 32 + ((lane >> 4) * 8);
      s16x8 af[4], bfr[4];
      #pragma unroll
      for (int m = 0; m < 4; ++m)
        af[m] = *(const s16x8*)&As[(wr * 64 + m * 16 + (lane & 15)) * 64 + ko];
      #pragma unroll
      for (int nn = 0; nn < 4; ++nn)
        bfr[nn] = *(const s16x8*)&Bs[(wc * 64 + nn * 16 + (lane & 15)) * 64 + ko];
      #pragma unroll
      for (int m = 0; m < 4; ++m)
        #pragma unroll
        for (int nn = 0; nn < 4; ++nn)
          acc[m][nn] = __builtin_amdgcn_mfma_f32_16x16x32_bf16(af[m], bfr[nn], acc[m][nn], 0, 0, 0);
    }
  }

  #pragma unroll
  for (int m = 0; m < 4; ++m) {
    #pragma unroll
    for (int nn = 0; nn < 4; ++nn) {
      int r0 = m0 + wr * 64 + m * 16 + ((lane >> 4) * 4);
      int cc = n0 + wc * 64 + nn * 16 + (lane & 15);
      #pragma unroll
      for (int j = 0; j < 4; ++j) {
        float val = acc[m][nn][j];
        if (F32OUT) ((float*)Cp)[(size_t)(r0 + j) * Nn + cc] = val;
        else        ((unsigned short*)Cp)[(size_t)(r0 + j) * Nn + cc] = f2bf(val);
      }
    }
  }
}

// ---------------------------------------------------------------------------
// K5: RoPE apply + reshape qkv_tmp[4096][3072] -> q/k [b*H][n][64] bf16
// q additionally scaled by 1/sqrt(64)=0.125 (folded attention scale)
// ---------------------------------------------------------------------------
__global__ __launch_bounds__(256) void k_rope(const unsigned short* __restrict__ qkv,
                                              const float2* __restrict__ tab,
                                              unsigned short* __restrict__ q,
                                              unsigned short* __restrict__ k) {
  int bs = blockIdx.x;
  int bb = bs / NN, s = bs % NN;
  int lane = threadIdx.x & 63, wv = threadIdx.x >> 6;
  #pragma unroll
  for (int g = wv; g < 32; g += 4) {
    int i3 = g >> 4, h = g & 15;
    float val = bf2f(qkv[(size_t)bs * QKVN + g * 64 + lane]);
    float partner = __shfl_xor(val, 1);
    float2 cs = tab[(size_t)bs * 32 + (lane >> 1)];
    float out;
    if ((lane & 1) == 0) out = val * cs.x - partner * cs.y;      // t1*cos - t2*sin
    else                 out = partner * cs.y + val * cs.x;      // t1*sin + t2*cos
    if (i3 == 0) out *= 0.125f;
    unsigned short* dst = (i3 == 0) ? q : k;
    dst[((size_t)(bb * HH + h) * NN + s) * 64 + lane] = f2bf(out);
  }
}

// ---------------------------------------------------------------------------
// K5b: V transpose: qkvt[.][2048+h*64+dh] -> vT[bh][dh][s]  (bf16)
// ---------------------------------------------------------------------------
__global__ __launch_bounds__(256) void k_vtr(const unsigned short* __restrict__ qkvt,
                                             unsigned short* __restrict__ vT) {
  __shared__ unsigned short t[64][72];
  int s0 = blockIdx.x * 64, bh = blockIdx.y, bb = bh >> 4, h = bh & 15;
  int tid = threadIdx.x;
  int r = tid >> 2, c0 = (tid & 3) * 16;
  int cw = c0 ^ (((r >> 4) & 3) << 4);
  const unsigned short* src = qkvt + (size_t)(bb * NN + s0 + r) * QKVN + 2048 + h * 64 + c0;
  *(s16x8*)&t[r][cw]     = *(const s16x8*)src;
  *(s16x8*)&t[r][cw + 8] = *(const s16x8*)(src + 8);
  __syncthreads();
  int dh = tid >> 2, sc = (tid & 3) * 16;
  int col2 = dh ^ ((tid & 3) << 4);
  s16x8 o1, o2;
  #pragma unroll
  for (int i = 0; i < 8; ++i) {
    o1[i] = (short)t[sc + i][col2];
    o2[i] = (short)t[sc + 8 + i][col2];
  }
  unsigned short* dst = vT + ((size_t)bh * 64 + dh) * NN + s0 + sc;
  *(s16x8*)dst       = o1;
  *(s16x8*)(dst + 8) = o2;
}

// ---------------------------------------------------------------------------
// K6: flash attention, LDS-staged K/V (double-buffered, XOR-swizzled),
// fixed-max softmax via cubic softcap: p = exp(s - s^3/7500) (1 trans/elem),
// e^-50 max-shift cancels in normalization. 4 waves x 16 q-rows.
// ---------------------------------------------------------------------------
__global__ __launch_bounds__(256) void k_attn(const unsigned short* __restrict__ q,
                                              const unsigned short* __restrict__ k,
                                              const unsigned short* __restrict__ vT,
                                              const int* __restrict__ mods,
                                              unsigned short* __restrict__ o) {
  __shared__ unsigned short Ks[2][64 * 64];
  __shared__ unsigned short Vs[2][64 * 64];
  __shared__ unsigned short Pw[4][16][72];
  int tid = threadIdx.x;
  int lane = tid & 63, wv = tid >> 6;
  int lo = lane & 15, hi = lane >> 4;

  int fid = blockIdx.y * gridDim.x + blockIdx.x;      // 0..1023
  int nid = (fid & 7) * 128 + (fid >> 3);             // XCD-contiguous
  int bh = nid >> 5;
  int qt = nid & 31;
  int q0 = (31 - qt) * 64;                            // longest-first
  int bb = bh >> 4;
  int q0w = q0 + wv * 16;

  const unsigned short* qb = q + (size_t)bh * NN * 64;
  const unsigned short* kb = k + (size_t)bh * NN * 64;
  const unsigned short* vb = vT + (size_t)bh * 64 * NN;

  s16x8 qf[2];
  {
    int qrow = q0w + lo;
    #pragma unroll
    for (int ks = 0; ks < 2; ++ks)
      qf[ks] = *(const s16x8*)&qb[(size_t)qrow * 64 + ks * 32 + hi * 8];
  }

  int off_[MMOD], end_[MMOD];
  #pragma unroll
  for (int m = 0; m < MMOD; ++m) {
    off_[m] = mods[(bb * MMOD + m) * 3 + 1];
    end_[m] = off_[m] + mods[(bb * MMOD + m) * 3 + 2];
  }
  int limit[4];
  #pragma unroll
  for (int j = 0; j < 4; ++j) {
    int r = q0w + hi * 4 + j;
    int L = r + 1;
    #pragma unroll
    for (int m = 0; m < MMOD; ++m)
      if (off_[m] <= r && end_[m] > L) L = end_[m];
    limit[j] = L;
  }
  int minlim, kvmax_w, Lblk;
  {
    int L = q0w + 1;
    #pragma unroll
    for (int m = 0; m < MMOD; ++m)
      if (off_[m] <= q0w && end_[m] > L) L = end_[m];
    minlim = L;
    int r = q0w + 15;
    int L2 = r + 1;
    #pragma unroll
    for (int m = 0; m < MMOD; ++m)
      if (off_[m] <= r && end_[m] > L2) L2 = end_[m];
    kvmax_w = L2;
    int rb = q0 + 63;
    int L3 = rb + 1;
    #pragma unroll
    for (int m = 0; m < MMOD; ++m)
      if (off_[m] <= rb && end_[m] > L3) L3 = end_[m];
    Lblk = L3;
  }
  int nt = (Lblk + 63) >> 6;

  #define STAGE_KV(B, KV0) do { \
    _Pragma("unroll") \
    for (int i_ = 0; i_ < 2; ++i_) { \
      int r_ = (wv * 2 + i_) * 8 + (lane >> 3); \
      int cs_ = (lane & 7) ^ ((lane >> 3) & 7); \
      const unsigned short* gK_ = kb + (size_t)((KV0) + r_) * 64 + cs_ * 8; \
      ASYNC_LDS16(gK_, &Ks[B][(wv * 2 + i_) * 512]); \
      const unsigned short* gV_ = vb + (size_t)r_ * NN + (KV0) + cs_ * 8; \
      ASYNC_LDS16(gV_, &Vs[B][(wv * 2 + i_) * 512]); \
    } \
  } while (0)

  float lrunp[4] = {0.f, 0.f, 0.f, 0.f};
  f32x4 accO[4] = {};

  STAGE_KV(0, 0);
  __syncthreads();
  int buf = 0;
  for (int t = 0; t < nt; ++t) {
    if (t + 1 < nt) STAGE_KV(buf ^ 1, (t + 1) << 6);
    int kv0 = t << 6;
    if (kv0 < kvmax_w) {
      // QK^T from swizzled LDS
      f32x4 sv[4];
      #pragma unroll
      for (int cb = 0; cb < 4; ++cb) {
        int krow = cb * 16 + lo;
        int c0 = (hi) ^ (krow & 7);
        int c1 = (4 + hi) ^ (krow & 7);
        s16x8 kf0 = *(const s16x8*)&Ks[buf][krow * 64 + c0 * 8];
        s16x8 kf1 = *(const s16x8*)&Ks[buf][krow * 64 + c1 * 8];
        f32x4 z = {};
        z = __builtin_amdgcn_mfma_f32_16x16x32_bf16(qf[0], kf0, z, 0, 0, 0);
        z = __builtin_amdgcn_mfma_f32_16x16x32_bf16(qf[1], kf1, z, 0, 0, 0);
        sv[cb] = z;
      }

      // p = exp(50 tanh(s/50)) ~= exp(s - s^3/7500); e^-50 shift cancels.
      // bf16-truncate p; denominator accumulates the truncated value.
      if (kv0 + 64 <= minlim) {
        #pragma unroll
        for (int cb = 0; cb < 4; ++cb)
          #pragma unroll
          for (int j = 0; j < 4; ++j) {
            float s = sv[cb][j];
            float cap = __builtin_fmaf(-(s * s), s * 1.3333333e-4f, s);
            cap = __builtin_amdgcn_fmed3f(cap, -50.f, 50.f);
            float p = __expf(cap);
            unsigned int up = __float_as_uint(p) & 0xffff0000u;
            lrunp[j] += __uint_as_float(up);
            Pw[wv][hi * 4 + j][cb * 16 + lo] = (unsigned short)(up >> 16);
          }
      } else {
        #pragma unroll
        for (int cb = 0; cb < 4; ++cb) {
          int col = kv0 + cb * 16 + lo;
          #pragma unroll
          for (int j = 0; j < 4; ++j) {
            float s = sv[cb][j];
            float cap = __builtin_fmaf(-(s * s), s * 1.3333333e-4f, s);
            cap = __builtin_amdgcn_fmed3f(cap, -50.f, 50.f);
            float p = __expf(cap);
            if (col >= limit[j]) p = 0.f;
            unsigned int up = __float_as_uint(p) & 0xffff0000u;
            lrunp[j] += __uint_as_float(up);
            Pw[wv][hi * 4 + j][cb * 16 + lo] = (unsigned short)(up >> 16);
          }
        }
      }

      // PV from swizzled LDS
      #pragma unroll
      for (int ks = 0; ks < 2; ++ks) {
        s16x8 pa = *(const s16x8*)&Pw[wv][lo][ks * 32 + hi * 8];
        #pragma unroll
        for (int cb = 0; cb < 4; ++cb) {
          int vrow = cb * 16 + lo;
          int vc = (ks * 4 + hi) ^ (vrow & 7);
          s16x8 vf = *(const s16x8*)&Vs[buf][vrow * 64 + vc * 8];
          accO[cb] = __builtin_amdgcn_mfma_f32_16x16x32_bf16(pa, vf, accO[cb], 0, 0, 0);
        }
      }
    }
    __syncthreads();
    buf ^= 1;
  }

  #pragma unroll
  for (int o2 = 1; o2 < 16; o2 <<= 1)
    #pragma unroll
    for (int j = 0; j < 4; ++j) lrunp[j] += __shfl_xor(lrunp[j], o2);

  int h = bh & 15;
  float rl[4];
  #pragma unroll
  for (int j = 0; j < 4; ++j) rl[j] = __builtin_amdgcn_rcpf(lrunp[j]);
  #pragma unroll
  for (int cb = 0; cb < 4; ++cb)
    #pragma unroll
    for (int j = 0; j < 4; ++j) {
      int r = q0w + hi * 4 + j;
      float val = accO[cb][j] * rl[j];
      o[((size_t)(bb * NN) + r) * (HH * DHD) + h * 64 + cb * 16 + lo] = f2bf(val);
    }
}

// ---------------------------------------------------------------------------
extern "C" void kernel_launch(void* const* d_in, const int* in_sizes, int n_in,
                              void* d_out, int out_size, void* d_ws, size_t ws_size,
                              hipStream_t stream) {
  (void)in_sizes; (void)n_in; (void)out_size; (void)ws_size;
  const float* x      = (const float*)d_in[0];
  const float* tokens = (const float*)d_in[1];
  const float* gamma  = (const float*)d_in[2];
  const float* w_qkv  = (const float*)d_in[3];
  const float* w_out  = (const float*)d_in[4];
  const int*   mods   = (const int*)d_in[5];

  char* ws = (char*)d_ws;
  unsigned short* xn    = (unsigned short*)(ws + 0);           //  8 MB
  unsigned short* wqkvT = (unsigned short*)(ws + 8388608);     //  6 MB
  unsigned short* woutT = (unsigned short*)(ws + 14680064);    //  2 MB
  unsigned short* qkvt  = (unsigned short*)(ws + 16777216);    // 24 MB
  unsigned short* qd    = (unsigned short*)(ws + 41943040);    //  8 MB
  unsigned short* kd    = (unsigned short*)(ws + 50331648);    //  8 MB
  unsigned short* vTd   = (unsigned short*)(ws + 58720256);    //  8 MB
  unsigned short* attno = (unsigned short*)(ws + 67108864);    //  8 MB
  int*            pos   = (int*)(ws + 75497472);               // 16 KB
  float2*         tab   = (float2*)(ws + 75513856);            //  1 MB

  k_prep<<<BNROWS, 256, 0, stream>>>(x, tokens, gamma, mods, xn);
  k_pos<<<BB, 64, 0, stream>>>(mods, pos);
  k_tab<<<(BB * NN * 32) / 256, 256, 0, stream>>>(pos, tab);
  k_tr<<<dim3(QKVN / 32, DD / 32), dim3(32, 8), 0, stream>>>(w_qkv, wqkvT, DD, QKVN);
  k_tr<<<dim3((HH * DHD) / 32, DD / 32), dim3(32, 8), 0, stream>>>(w_out, woutT, HH * DHD, DD);
  k_gemm<false><<<dim3(QKVN / 128, BNROWS / 128), 256, 0, stream>>>(xn, wqkvT, (void*)qkvt, BNROWS, QKVN, DD);
  k_rope<<<BNROWS, 256, 0, stream>>>(qkvt, tab, qd, kd);
  k_vtr<<<dim3(NN / 64, BB * HH), 256, 0, stream>>>(qkvt, vTd);
  k_attn<<<dim3(NN / 64, BB * HH), 256, 0, stream>>>(qd, kd, vTd, mods, attno);
  k_gemm<true><<<dim3(DD / 128, BNROWS / 128), 256, 0, stream>>>(attno, woutT, d_out, BNROWS, DD, DD);
}

// Round 5
// 155.526 us; speedup vs baseline: 2.1503x; 1.0721x over previous
//
#include <hip/hip_runtime.h>
#include <stdint.h>

#define HH 16
#define DHD 64
#define BB 2
#define NN 2048
#define DD 1024
#define MMOD 4
#define LMAX 256
#define BNROWS (BB*NN)      // 4096
#define QKVN (3*HH*DHD)     // 3072

typedef __attribute__((ext_vector_type(4))) float f32x4;
typedef __attribute__((ext_vector_type(8))) short s16x8;

__device__ __forceinline__ float bf2f(unsigned short b) {
  return __uint_as_float(((unsigned int)b) << 16);
}
__device__ __forceinline__ unsigned short f2bf(float f) {
  unsigned int u = __float_as_uint(f);
  u += 0x7fffu + ((u >> 16) & 1u);
  return (unsigned short)(u >> 16);
}

#define ASYNC_LDS16(g, l) \
  __builtin_amdgcn_global_load_lds((const __attribute__((address_space(1))) void*)(g), \
                                   (__attribute__((address_space(3))) void*)(l), 16, 0, 0)

// ---------------------------------------------------------------------------
// K1: modality splice + norm + gamma, write xn bf16 [4096][1024]
// ---------------------------------------------------------------------------
__global__ __launch_bounds__(256) void k_prep(const float* __restrict__ x,
                                              const float* __restrict__ tokens,
                                              const float* __restrict__ gamma,
                                              const int* __restrict__ mods,
                                              unsigned short* __restrict__ xn) {
  int bs = blockIdx.x;
  int bb = bs / NN, s = bs % NN;
  int t = threadIdx.x;
  int c = t * 4;
  const float4 xv = *(const float4*)(x + (size_t)bs * DD + c);
  float4 acc = {0.f, 0.f, 0.f, 0.f};
  bool any = false;
  #pragma unroll
  for (int m = 0; m < MMOD; ++m) {
    int off = mods[(bb * MMOD + m) * 3 + 1];
    int ln  = mods[(bb * MMOD + m) * 3 + 2];
    if (s >= off && s < off + ln) {
      any = true;
      int rel = s - off;
      if (rel > LMAX - 1) rel = LMAX - 1;
      if (rel < 0) rel = 0;
      const float4 tv = *(const float4*)(tokens + ((size_t)(bb * MMOD + m) * LMAX + rel) * DD + c);
      acc.x += tv.x; acc.y += tv.y; acc.z += tv.z; acc.w += tv.w;
    }
  }
  float4 v = any ? acc : xv;
  float ss = v.x*v.x + v.y*v.y + v.z*v.z + v.w*v.w;
  #pragma unroll
  for (int o = 32; o; o >>= 1) ss += __shfl_xor(ss, o);
  __shared__ float red[4];
  int wv = t >> 6;
  if ((t & 63) == 0) red[wv] = ss;
  __syncthreads();
  float tot = red[0] + red[1] + red[2] + red[3];
  float norm = sqrtf(tot);
  norm = fmaxf(norm, 1e-12f);
  float sc = 32.0f / norm;   // sqrt(1024) = 32
  const float4 g = *(const float4*)(gamma + c);
  unsigned long long pk =
      (unsigned long long)f2bf(v.x * sc * (g.x + 1.f)) |
      ((unsigned long long)f2bf(v.y * sc * (g.y + 1.f)) << 16) |
      ((unsigned long long)f2bf(v.z * sc * (g.z + 1.f)) << 32) |
      ((unsigned long long)f2bf(v.w * sc * (g.w + 1.f)) << 48);
  *(unsigned long long*)(xn + (size_t)bs * DD + c) = pk;
}

// ---------------------------------------------------------------------------
// K2: pos[b][n] = s - cumsum(rot_any). One wave per batch.
// ---------------------------------------------------------------------------
__global__ void k_pos(const int* __restrict__ mods, int* __restrict__ pos) {
  int bb = blockIdx.x;
  int lane = threadIdx.x;       // 64
  int offs[MMOD], ends[MMOD];
  #pragma unroll
  for (int m = 0; m < MMOD; ++m) {
    int off = mods[(bb * MMOD + m) * 3 + 1];
    int ln  = mods[(bb * MMOD + m) * 3 + 2];
    offs[m] = off + 1;
    ends[m] = off + ln;
  }
  int base = lane * (NN / 64);  // 32 per lane
  int lc[NN / 64];
  int tot = 0;
  #pragma unroll
  for (int i = 0; i < NN / 64; ++i) {
    int s = base + i;
    int f = 0;
    #pragma unroll
    for (int m = 0; m < MMOD; ++m)
      if (s >= offs[m] && s < ends[m]) f = 1;
    tot += f;
    lc[i] = tot;
  }
  int v = tot;
  #pragma unroll
  for (int o = 1; o < 64; o <<= 1) {
    int u = __shfl_up(v, o);
    if (lane >= o) v += u;
  }
  int excl = v - tot;
  #pragma unroll
  for (int i = 0; i < NN / 64; ++i)
    pos[bb * NN + base + i] = base + i - (excl + lc[i]);
}

// ---------------------------------------------------------------------------
// K2b: RoPE cos/sin table [b*n][32] float2
// ---------------------------------------------------------------------------
__global__ void k_tab(const int* __restrict__ pos, float2* __restrict__ tab) {
  int gid = blockIdx.x * 256 + threadIdx.x;   // b*n*32 = 131072
  int p = gid & 31;
  int bs = gid >> 5;
  float inv = expf(-((float)p / 32.f) * 9.210340371976184f); // 1/10000^(2p/64)
  float ang = (float)pos[bs] * inv;
  float sn, cs;
  sincosf(ang, &sn, &cs);
  tab[gid] = make_float2(cs, sn);
}

// ---------------------------------------------------------------------------
// K3: transpose f32 [R][C] -> bf16 [C][R]
// ---------------------------------------------------------------------------
__global__ void k_tr(const float* __restrict__ in, unsigned short* __restrict__ out,
                     int R, int C) {
  __shared__ float tile[32][33];
  int bx = blockIdx.x, by = blockIdx.y;
  int tx = threadIdx.x, ty = threadIdx.y;
  #pragma unroll
  for (int k = 0; k < 4; ++k) {
    int r = by * 32 + ty + k * 8, c = bx * 32 + tx;
    tile[ty + k * 8][tx] = in[(size_t)r * C + c];
  }
  __syncthreads();
  #pragma unroll
  for (int k = 0; k < 4; ++k) {
    int oc = bx * 32 + ty + k * 8;
    int orr = by * 32 + tx;
    out[(size_t)oc * R + orr] = f2bf(tile[tx][ty + k * 8]);
  }
}

// ---------------------------------------------------------------------------
// K4/K7: GEMM  C[M][Nn] = A[M][K](bf16) * Bt[Nn][K](bf16)^T
// 128x128 tile, BK=64, 4 waves, 16x16x32 MFMA, global_load_lds staging,
// chunked XCD swizzle (grid % 8 == 0).
// ---------------------------------------------------------------------------
template<bool F32OUT>
__global__ __launch_bounds__(256) void k_gemm(const unsigned short* __restrict__ A,
                                              const unsigned short* __restrict__ Bt,
                                              void* __restrict__ Cp,
                                              int M, int Nn, int K) {
  __shared__ unsigned short As[128 * 64];
  __shared__ unsigned short Bs[128 * 64];
  int tid = threadIdx.x;
  int lane = tid & 63, wv = tid >> 6;
  int nb = gridDim.x * gridDim.y;
  int fid = blockIdx.y * gridDim.x + blockIdx.x;
  int cpx = nb >> 3;
  int nid = (fid & 7) * cpx + (fid >> 3);      // contiguous chunk per XCD
  int m0 = (nid / gridDim.x) * 128;
  int n0 = (nid % gridDim.x) * 128;
  int wr = wv >> 1, wc = wv & 1;
  f32x4 acc[4][4] = {};

  for (int kt = 0; kt < K; kt += 64) {
    __syncthreads();
    #pragma unroll
    for (int is = 0; is < 4; ++is) {
      int li = is * 256 + tid;
      int r = li >> 3, cc = (li & 7) * 8;
      const unsigned short* ga = A  + (size_t)(m0 + r) * K + kt + cc;
      const unsigned short* gb = Bt + (size_t)(n0 + r) * K + kt + cc;
      unsigned short* la = &As[(is * 256 + wv * 64) * 8];
      unsigned short* lb = &Bs[(is * 256 + wv * 64) * 8];
      ASYNC_LDS16(ga, la);
      ASYNC_LDS16(gb, lb);
    }
    __syncthreads();
    #pragma unroll
    for (int ks = 0; ks < 2; ++ks) {
      int ko = ks * 32 + ((lane >> 4) * 8);
      s16x8 af[4], bfr[4];
      #pragma unroll
      for (int m = 0; m < 4; ++m)
        af[m] = *(const s16x8*)&As[(wr * 64 + m * 16 + (lane & 15)) * 64 + ko];
      #pragma unroll
      for (int nn = 0; nn < 4; ++nn)
        bfr[nn] = *(const s16x8*)&Bs[(wc * 64 + nn * 16 + (lane & 15)) * 64 + ko];
      #pragma unroll
      for (int m = 0; m < 4; ++m)
        #pragma unroll
        for (int nn = 0; nn < 4; ++nn)
          acc[m][nn] = __builtin_amdgcn_mfma_f32_16x16x32_bf16(af[m], bfr[nn], acc[m][nn], 0, 0, 0);
    }
  }

  #pragma unroll
  for (int m = 0; m < 4; ++m) {
    #pragma unroll
    for (int nn = 0; nn < 4; ++nn) {
      int r0 = m0 + wr * 64 + m * 16 + ((lane >> 4) * 4);
      int cc = n0 + wc * 64 + nn * 16 + (lane & 15);
      #pragma unroll
      for (int j = 0; j < 4; ++j) {
        float val = acc[m][nn][j];
        if (F32OUT) ((float*)Cp)[(size_t)(r0 + j) * Nn + cc] = val;
        else        ((unsigned short*)Cp)[(size_t)(r0 + j) * Nn + cc] = f2bf(val);
      }
    }
  }
}

// ---------------------------------------------------------------------------
// K5: RoPE apply + reshape qkv_tmp[4096][3072] -> q/k [b*H][n][64] bf16
// q additionally scaled by 1/sqrt(64)=0.125 (folded attention scale)
// ---------------------------------------------------------------------------
__global__ __launch_bounds__(256) void k_rope(const unsigned short* __restrict__ qkv,
                                              const float2* __restrict__ tab,
                                              unsigned short* __restrict__ q,
                                              unsigned short* __restrict__ k) {
  int bs = blockIdx.x;
  int bb = bs / NN, s = bs % NN;
  int lane = threadIdx.x & 63, wv = threadIdx.x >> 6;
  #pragma unroll
  for (int g = wv; g < 32; g += 4) {
    int i3 = g >> 4, h = g & 15;
    float val = bf2f(qkv[(size_t)bs * QKVN + g * 64 + lane]);
    float partner = __shfl_xor(val, 1);
    float2 cs = tab[(size_t)bs * 32 + (lane >> 1)];
    float out;
    if ((lane & 1) == 0) out = val * cs.x - partner * cs.y;      // t1*cos - t2*sin
    else                 out = partner * cs.y + val * cs.x;      // t1*sin + t2*cos
    if (i3 == 0) out *= 0.125f;
    unsigned short* dst = (i3 == 0) ? q : k;
    dst[((size_t)(bb * HH + h) * NN + s) * 64 + lane] = f2bf(out);
  }
}

// ---------------------------------------------------------------------------
// K5b: V transpose: qkvt[.][2048+h*64+dh] -> vT[bh][dh][s]  (bf16)
// ---------------------------------------------------------------------------
__global__ __launch_bounds__(256) void k_vtr(const unsigned short* __restrict__ qkvt,
                                             unsigned short* __restrict__ vT) {
  __shared__ unsigned short t[64][72];
  int s0 = blockIdx.x * 64, bh = blockIdx.y, bb = bh >> 4, h = bh & 15;
  int tid = threadIdx.x;
  int r = tid >> 2, c0 = (tid & 3) * 16;
  int cw = c0 ^ (((r >> 4) & 3) << 4);
  const unsigned short* src = qkvt + (size_t)(bb * NN + s0 + r) * QKVN + 2048 + h * 64 + c0;
  *(s16x8*)&t[r][cw]     = *(const s16x8*)src;
  *(s16x8*)&t[r][cw + 8] = *(const s16x8*)(src + 8);
  __syncthreads();
  int dh = tid >> 2, sc = (tid & 3) * 16;
  int col2 = dh ^ ((tid & 3) << 4);
  s16x8 o1, o2;
  #pragma unroll
  for (int i = 0; i < 8; ++i) {
    o1[i] = (short)t[sc + i][col2];
    o2[i] = (short)t[sc + 8 + i][col2];
  }
  unsigned short* dst = vT + ((size_t)bh * 64 + dh) * NN + s0 + sc;
  *(s16x8*)dst       = o1;
  *(s16x8*)(dst + 8) = o2;
}

// ---------------------------------------------------------------------------
// K6: flash attention. Paired q-tiles per block: 8 waves, waves 0-3 on the
// long tile (31-bx), waves 4-7 on the mirror short tile (bx); shared K/V
// double-buffer staging. Fixed-max softmax via cubic softcap (1 trans/elem).
// ---------------------------------------------------------------------------
__global__ __launch_bounds__(512) void k_attn(const unsigned short* __restrict__ q,
                                              const unsigned short* __restrict__ k,
                                              const unsigned short* __restrict__ vT,
                                              const int* __restrict__ mods,
                                              unsigned short* __restrict__ o) {
  __shared__ unsigned short Ks[2][64 * 64];
  __shared__ unsigned short Vs[2][64 * 64];
  __shared__ unsigned short Pw[8][16][72];
  int tid = threadIdx.x;
  int lane = tid & 63, wv = tid >> 6;
  int lo = lane & 15, hi = lane >> 4;

  int fid = blockIdx.y * gridDim.x + blockIdx.x;      // 0..511
  int nid = (fid & 7) * 64 + (fid >> 3);              // XCD-contiguous
  int bh = nid >> 4;
  int bx = nid & 15;
  int bb = bh >> 4;
  int q0A = (31 - bx) * 64;                           // long tile
  int q0B = bx * 64;                                  // mirror short tile
  int q0w = ((wv < 4) ? q0A : q0B) + (wv & 3) * 16;

  const unsigned short* qb = q + (size_t)bh * NN * 64;
  const unsigned short* kb = k + (size_t)bh * NN * 64;
  const unsigned short* vb = vT + (size_t)bh * 64 * NN;

  s16x8 qf[2];
  {
    int qrow = q0w + lo;
    #pragma unroll
    for (int ks = 0; ks < 2; ++ks)
      qf[ks] = *(const s16x8*)&qb[(size_t)qrow * 64 + ks * 32 + hi * 8];
  }

  int off_[MMOD], end_[MMOD];
  #pragma unroll
  for (int m = 0; m < MMOD; ++m) {
    off_[m] = mods[(bb * MMOD + m) * 3 + 1];
    end_[m] = off_[m] + mods[(bb * MMOD + m) * 3 + 2];
  }
  int limit[4];
  #pragma unroll
  for (int j = 0; j < 4; ++j) {
    int r = q0w + hi * 4 + j;
    int L = r + 1;
    #pragma unroll
    for (int m = 0; m < MMOD; ++m)
      if (off_[m] <= r && end_[m] > L) L = end_[m];
    limit[j] = L;
  }
  int minlim, kvmax_w;
  {
    int L = q0w + 1;
    #pragma unroll
    for (int m = 0; m < MMOD; ++m)
      if (off_[m] <= q0w && end_[m] > L) L = end_[m];
    minlim = L;
    int r = q0w + 15;
    int L2 = r + 1;
    #pragma unroll
    for (int m = 0; m < MMOD; ++m)
      if (off_[m] <= r && end_[m] > L2) L2 = end_[m];
    kvmax_w = L2;
  }
  int nt;
  {
    int ra = q0A + 63;
    int LA = ra + 1;
    #pragma unroll
    for (int m = 0; m < MMOD; ++m)
      if (off_[m] <= ra && end_[m] > LA) LA = end_[m];
    int rb2 = q0B + 63;
    int LB = rb2 + 1;
    #pragma unroll
    for (int m = 0; m < MMOD; ++m)
      if (off_[m] <= rb2 && end_[m] > LB) LB = end_[m];
    int Lblk = (LA > LB) ? LA : LB;
    nt = (Lblk + 63) >> 6;
  }

  // 512 threads stage one 16B chunk each of K and V per tile.
  #define STAGE_KV(B, KV0) do { \
    int r_ = tid >> 3; \
    int cs_ = (lane & 7) ^ ((lane >> 3) & 7); \
    const unsigned short* gK_ = kb + (size_t)((KV0) + r_) * 64 + cs_ * 8; \
    ASYNC_LDS16(gK_, &Ks[B][wv * 512]); \
    const unsigned short* gV_ = vb + (size_t)r_ * NN + (KV0) + cs_ * 8; \
    ASYNC_LDS16(gV_, &Vs[B][wv * 512]); \
  } while (0)

  float lrunp[4] = {0.f, 0.f, 0.f, 0.f};
  f32x4 accO[4] = {};

  STAGE_KV(0, 0);
  __syncthreads();
  int buf = 0;
  for (int t = 0; t < nt; ++t) {
    if (t + 1 < nt) STAGE_KV(buf ^ 1, (t + 1) << 6);
    int kv0 = t << 6;
    if (kv0 < kvmax_w) {
      // QK^T from swizzled LDS
      f32x4 sv[4];
      #pragma unroll
      for (int cb = 0; cb < 4; ++cb) {
        int krow = cb * 16 + lo;
        int c0 = (hi) ^ (krow & 7);
        int c1 = (4 + hi) ^ (krow & 7);
        s16x8 kf0 = *(const s16x8*)&Ks[buf][krow * 64 + c0 * 8];
        s16x8 kf1 = *(const s16x8*)&Ks[buf][krow * 64 + c1 * 8];
        f32x4 z = {};
        z = __builtin_amdgcn_mfma_f32_16x16x32_bf16(qf[0], kf0, z, 0, 0, 0);
        z = __builtin_amdgcn_mfma_f32_16x16x32_bf16(qf[1], kf1, z, 0, 0, 0);
        sv[cb] = z;
      }

      // p = exp(50 tanh(s/50)) ~= exp(s - s^3/7500); e^-50 shift cancels.
      if (kv0 + 64 <= minlim) {
        #pragma unroll
        for (int cb = 0; cb < 4; ++cb)
          #pragma unroll
          for (int j = 0; j < 4; ++j) {
            float s = sv[cb][j];
            float t2 = s * s;
            float u = __builtin_fmaf(t2, -1.3333333e-4f, 1.0f);
            float cap = __builtin_amdgcn_fmed3f(s * u, -50.f, 50.f);
            float p = __expf(cap);
            lrunp[j] += p;
            Pw[wv][hi * 4 + j][cb * 16 + lo] =
                (unsigned short)(__float_as_uint(p) >> 16);
          }
      } else {
        #pragma unroll
        for (int cb = 0; cb < 4; ++cb) {
          int col = kv0 + cb * 16 + lo;
          #pragma unroll
          for (int j = 0; j < 4; ++j) {
            float s = sv[cb][j];
            float t2 = s * s;
            float u = __builtin_fmaf(t2, -1.3333333e-4f, 1.0f);
            float cap = __builtin_amdgcn_fmed3f(s * u, -50.f, 50.f);
            float p = __expf(cap);
            if (col >= limit[j]) p = 0.f;
            lrunp[j] += p;
            Pw[wv][hi * 4 + j][cb * 16 + lo] =
                (unsigned short)(__float_as_uint(p) >> 16);
          }
        }
      }

      // PV from swizzled LDS
      #pragma unroll
      for (int ks = 0; ks < 2; ++ks) {
        s16x8 pa = *(const s16x8*)&Pw[wv][lo][ks * 32 + hi * 8];
        #pragma unroll
        for (int cb = 0; cb < 4; ++cb) {
          int vrow = cb * 16 + lo;
          int vc = (ks * 4 + hi) ^ (vrow & 7);
          s16x8 vf = *(const s16x8*)&Vs[buf][vrow * 64 + vc * 8];
          accO[cb] = __builtin_amdgcn_mfma_f32_16x16x32_bf16(pa, vf, accO[cb], 0, 0, 0);
        }
      }
    }
    __syncthreads();
    buf ^= 1;
  }

  #pragma unroll
  for (int o2 = 1; o2 < 16; o2 <<= 1)
    #pragma unroll
    for (int j = 0; j < 4; ++j) lrunp[j] += __shfl_xor(lrunp[j], o2);

  int h = bh & 15;
  float rl[4];
  #pragma unroll
  for (int j = 0; j < 4; ++j) rl[j] = __builtin_amdgcn_rcpf(lrunp[j]);
  #pragma unroll
  for (int cb = 0; cb < 4; ++cb)
    #pragma unroll
    for (int j = 0; j < 4; ++j) {
      int r = q0w + hi * 4 + j;
      float val = accO[cb][j] * rl[j];
      o[((size_t)(bb * NN) + r) * (HH * DHD) + h * 64 + cb * 16 + lo] = f2bf(val);
    }
}

// ---------------------------------------------------------------------------
extern "C" void kernel_launch(void* const* d_in, const int* in_sizes, int n_in,
                              void* d_out, int out_size, void* d_ws, size_t ws_size,
                              hipStream_t stream) {
  (void)in_sizes; (void)n_in; (void)out_size; (void)ws_size;
  const float* x      = (const float*)d_in[0];
  const float* tokens = (const float*)d_in[1];
  const float* gamma  = (const float*)d_in[2];
  const float* w_qkv  = (const float*)d_in[3];
  const float* w_out  = (const float*)d_in[4];
  const int*   mods   = (const int*)d_in[5];

  char* ws = (char*)d_ws;
  unsigned short* xn    = (unsigned short*)(ws + 0);           //  8 MB
  unsigned short* wqkvT = (unsigned short*)(ws + 8388608);     //  6 MB
  unsigned short* woutT = (unsigned short*)(ws + 14680064);    //  2 MB
  unsigned short* qkvt  = (unsigned short*)(ws + 16777216);    // 24 MB
  unsigned short* qd    = (unsigned short*)(ws + 41943040);    //  8 MB
  unsigned short* kd    = (unsigned short*)(ws + 50331648);    //  8 MB
  unsigned short* vTd   = (unsigned short*)(ws + 58720256);    //  8 MB
  unsigned short* attno = (unsigned short*)(ws + 67108864);    //  8 MB
  int*            pos   = (int*)(ws + 75497472);               // 16 KB
  float2*         tab   = (float2*)(ws + 75513856);            //  1 MB

  k_prep<<<BNROWS, 256, 0, stream>>>(x, tokens, gamma, mods, xn);
  k_pos<<<BB, 64, 0, stream>>>(mods, pos);
  k_tab<<<(BB * NN * 32) / 256, 256, 0, stream>>>(pos, tab);
  k_tr<<<dim3(QKVN / 32, DD / 32), dim3(32, 8), 0, stream>>>(w_qkv, wqkvT, DD, QKVN);
  k_tr<<<dim3((HH * DHD) / 32, DD / 32), dim3(32, 8), 0, stream>>>(w_out, woutT, HH * DHD, DD);
  k_gemm<false><<<dim3(QKVN / 128, BNROWS / 128), 256, 0, stream>>>(xn, wqkvT, (void*)qkvt, BNROWS, QKVN, DD);
  k_rope<<<BNROWS, 256, 0, stream>>>(qkvt, tab, qd, kd);
  k_vtr<<<dim3(NN / 64, BB * HH), 256, 0, stream>>>(qkvt, vTd);
  k_attn<<<dim3(16, BB * HH), 512, 0, stream>>>(qd, kd, vTd, mods, attno);
  k_gemm<true><<<dim3(DD / 128, BNROWS / 128), 256, 0, stream>>>(attno, woutT, d_out, BNROWS, DD, DD);
}

// Round 6
// 138.332 us; speedup vs baseline: 2.4175x; 1.1243x over previous
//
#include <hip/hip_runtime.h>
#include <stdint.h>

#define HH 16
#define DHD 64
#define BB 2
#define NN 2048
#define DD 1024
#define MMOD 4
#define LMAX 256
#define BNROWS (BB*NN)      // 4096
#define QKVN (3*HH*DHD)     // 3072

typedef __attribute__((ext_vector_type(4))) float f32x4;
typedef __attribute__((ext_vector_type(8))) short s16x8;

__device__ __forceinline__ float bf2f(unsigned short b) {
  return __uint_as_float(((unsigned int)b) << 16);
}
__device__ __forceinline__ unsigned short f2bf(float f) {
  unsigned int u = __float_as_uint(f);
  u += 0x7fffu + ((u >> 16) & 1u);
  return (unsigned short)(u >> 16);
}

#define ASYNC_LDS16(g, l) \
  __builtin_amdgcn_global_load_lds((const __attribute__((address_space(1))) void*)(g), \
                                   (__attribute__((address_space(3))) void*)(l), 16, 0, 0)

// ---------------------------------------------------------------------------
// K1: modality splice + norm + gamma, write xn bf16 [4096][1024]
// ---------------------------------------------------------------------------
__global__ __launch_bounds__(256) void k_prep(const float* __restrict__ x,
                                              const float* __restrict__ tokens,
                                              const float* __restrict__ gamma,
                                              const int* __restrict__ mods,
                                              unsigned short* __restrict__ xn) {
  int bs = blockIdx.x;
  int bb = bs / NN, s = bs % NN;
  int t = threadIdx.x;
  int c = t * 4;
  const float4 xv = *(const float4*)(x + (size_t)bs * DD + c);
  float4 acc = {0.f, 0.f, 0.f, 0.f};
  bool any = false;
  #pragma unroll
  for (int m = 0; m < MMOD; ++m) {
    int off = mods[(bb * MMOD + m) * 3 + 1];
    int ln  = mods[(bb * MMOD + m) * 3 + 2];
    if (s >= off && s < off + ln) {
      any = true;
      int rel = s - off;
      if (rel > LMAX - 1) rel = LMAX - 1;
      if (rel < 0) rel = 0;
      const float4 tv = *(const float4*)(tokens + ((size_t)(bb * MMOD + m) * LMAX + rel) * DD + c);
      acc.x += tv.x; acc.y += tv.y; acc.z += tv.z; acc.w += tv.w;
    }
  }
  float4 v = any ? acc : xv;
  float ss = v.x*v.x + v.y*v.y + v.z*v.z + v.w*v.w;
  #pragma unroll
  for (int o = 32; o; o >>= 1) ss += __shfl_xor(ss, o);
  __shared__ float red[4];
  int wv = t >> 6;
  if ((t & 63) == 0) red[wv] = ss;
  __syncthreads();
  float tot = red[0] + red[1] + red[2] + red[3];
  float norm = sqrtf(tot);
  norm = fmaxf(norm, 1e-12f);
  float sc = 32.0f / norm;   // sqrt(1024) = 32
  const float4 g = *(const float4*)(gamma + c);
  unsigned long long pk =
      (unsigned long long)f2bf(v.x * sc * (g.x + 1.f)) |
      ((unsigned long long)f2bf(v.y * sc * (g.y + 1.f)) << 16) |
      ((unsigned long long)f2bf(v.z * sc * (g.z + 1.f)) << 32) |
      ((unsigned long long)f2bf(v.w * sc * (g.w + 1.f)) << 48);
  *(unsigned long long*)(xn + (size_t)bs * DD + c) = pk;
}

// ---------------------------------------------------------------------------
// K2: pos[b][n] = s - cumsum(rot_any). One wave per batch.
// ---------------------------------------------------------------------------
__global__ void k_pos(const int* __restrict__ mods, int* __restrict__ pos) {
  int bb = blockIdx.x;
  int lane = threadIdx.x;       // 64
  int offs[MMOD], ends[MMOD];
  #pragma unroll
  for (int m = 0; m < MMOD; ++m) {
    int off = mods[(bb * MMOD + m) * 3 + 1];
    int ln  = mods[(bb * MMOD + m) * 3 + 2];
    offs[m] = off + 1;
    ends[m] = off + ln;
  }
  int base = lane * (NN / 64);  // 32 per lane
  int lc[NN / 64];
  int tot = 0;
  #pragma unroll
  for (int i = 0; i < NN / 64; ++i) {
    int s = base + i;
    int f = 0;
    #pragma unroll
    for (int m = 0; m < MMOD; ++m)
      if (s >= offs[m] && s < ends[m]) f = 1;
    tot += f;
    lc[i] = tot;
  }
  int v = tot;
  #pragma unroll
  for (int o = 1; o < 64; o <<= 1) {
    int u = __shfl_up(v, o);
    if (lane >= o) v += u;
  }
  int excl = v - tot;
  #pragma unroll
  for (int i = 0; i < NN / 64; ++i)
    pos[bb * NN + base + i] = base + i - (excl + lc[i]);
}

// ---------------------------------------------------------------------------
// K2b: RoPE cos/sin table [b*n][32] float2
// ---------------------------------------------------------------------------
__global__ void k_tab(const int* __restrict__ pos, float2* __restrict__ tab) {
  int gid = blockIdx.x * 256 + threadIdx.x;   // b*n*32 = 131072
  int p = gid & 31;
  int bs = gid >> 5;
  float inv = expf(-((float)p / 32.f) * 9.210340371976184f); // 1/10000^(2p/64)
  float ang = (float)pos[bs] * inv;
  float sn, cs;
  sincosf(ang, &sn, &cs);
  tab[gid] = make_float2(cs, sn);
}

// ---------------------------------------------------------------------------
// K3: transpose f32 [R][C] -> bf16 [C][R]
// ---------------------------------------------------------------------------
__global__ void k_tr(const float* __restrict__ in, unsigned short* __restrict__ out,
                     int R, int C) {
  __shared__ float tile[32][33];
  int bx = blockIdx.x, by = blockIdx.y;
  int tx = threadIdx.x, ty = threadIdx.y;
  #pragma unroll
  for (int k = 0; k < 4; ++k) {
    int r = by * 32 + ty + k * 8, c = bx * 32 + tx;
    tile[ty + k * 8][tx] = in[(size_t)r * C + c];
  }
  __syncthreads();
  #pragma unroll
  for (int k = 0; k < 4; ++k) {
    int oc = bx * 32 + ty + k * 8;
    int orr = by * 32 + tx;
    out[(size_t)oc * R + orr] = f2bf(tile[tx][ty + k * 8]);
  }
}

// ---------------------------------------------------------------------------
// K4/K7: GEMM  C[M][Nn] = A[M][K](bf16) * Bt[Nn][K](bf16)^T
// 128x128 tile, BK=64, 4 waves, 16x16x32 MFMA.
// Double-buffered LDS (stage t+1 issued before compute t, one barrier/step)
// + XOR-swizzled tiles (pre-swizzled global source, swizzled ds_read),
// chunked XCD swizzle (grid % 8 == 0).
// ---------------------------------------------------------------------------
template<bool F32OUT>
__global__ __launch_bounds__(256) void k_gemm(const unsigned short* __restrict__ A,
                                              const unsigned short* __restrict__ Bt,
                                              void* __restrict__ Cp,
                                              int M, int Nn, int K) {
  __shared__ unsigned short As[2][128 * 64];
  __shared__ unsigned short Bs[2][128 * 64];
  int tid = threadIdx.x;
  int lane = tid & 63, wv = tid >> 6;
  int lo = lane & 15, hi = lane >> 4;
  int nb = gridDim.x * gridDim.y;
  int fid = blockIdx.y * gridDim.x + blockIdx.x;
  int cpx = nb >> 3;
  int nid = (fid & 7) * cpx + (fid >> 3);      // contiguous chunk per XCD
  int m0 = (nid / gridDim.x) * 128;
  int n0 = (nid % gridDim.x) * 128;
  int wr = wv >> 1, wc = wv & 1;
  f32x4 acc[4][4] = {};

  // stage: dest chunk li = is*256+tid (linear); source column-chunk
  // pre-swizzled: cs = (tid&7) ^ ((tid>>3)&7)  (row&7 of dest chunk)
  int srow = tid >> 3;                 // row within tile, +32 per is
  int scs  = ((tid & 7) ^ ((tid >> 3) & 7)) * 8;
  #define STAGE_G(BUF, KT) do { \
    _Pragma("unroll") \
    for (int is_ = 0; is_ < 4; ++is_) { \
      int r_ = is_ * 32 + srow; \
      const unsigned short* ga_ = A  + (size_t)(m0 + r_) * K + (KT) + scs; \
      const unsigned short* gb_ = Bt + (size_t)(n0 + r_) * K + (KT) + scs; \
      ASYNC_LDS16(ga_, &As[BUF][(is_ * 256 + wv * 64) * 8]); \
      ASYNC_LDS16(gb_, &Bs[BUF][(is_ * 256 + wv * 64) * 8]); \
    } \
  } while (0)

  int nt = K >> 6;
  STAGE_G(0, 0);
  __syncthreads();
  int buf = 0;
  for (int t = 0; t < nt; ++t) {
    if (t + 1 < nt) STAGE_G(buf ^ 1, (t + 1) << 6);
    #pragma unroll
    for (int ks = 0; ks < 2; ++ks) {
      s16x8 af[4], bfr[4];
      #pragma unroll
      for (int m = 0; m < 4; ++m) {
        int row = wr * 64 + m * 16 + lo;
        int cc = ((ks * 4 + hi) ^ (lo & 7)) * 8;
        af[m] = *(const s16x8*)&As[buf][row * 64 + cc];
      }
      #pragma unroll
      for (int nn = 0; nn < 4; ++nn) {
        int row = wc * 64 + nn * 16 + lo;
        int cc = ((ks * 4 + hi) ^ (lo & 7)) * 8;
        bfr[nn] = *(const s16x8*)&Bs[buf][row * 64 + cc];
      }
      #pragma unroll
      for (int m = 0; m < 4; ++m)
        #pragma unroll
        for (int nn = 0; nn < 4; ++nn)
          acc[m][nn] = __builtin_amdgcn_mfma_f32_16x16x32_bf16(af[m], bfr[nn], acc[m][nn], 0, 0, 0);
    }
    __syncthreads();
    buf ^= 1;
  }

  #pragma unroll
  for (int m = 0; m < 4; ++m) {
    #pragma unroll
    for (int nn = 0; nn < 4; ++nn) {
      int r0 = m0 + wr * 64 + m * 16 + hi * 4;
      int cc = n0 + wc * 64 + nn * 16 + lo;
      #pragma unroll
      for (int j = 0; j < 4; ++j) {
        float val = acc[m][nn][j];
        if (F32OUT) ((float*)Cp)[(size_t)(r0 + j) * Nn + cc] = val;
        else        ((unsigned short*)Cp)[(size_t)(r0 + j) * Nn + cc] = f2bf(val);
      }
    }
  }
}

// ---------------------------------------------------------------------------
// K5: RoPE apply + reshape qkv_tmp[4096][3072] -> q/k [b*H][n][64] bf16
// q additionally scaled by 1/sqrt(64)=0.125 (folded attention scale)
// ---------------------------------------------------------------------------
__global__ __launch_bounds__(256) void k_rope(const unsigned short* __restrict__ qkv,
                                              const float2* __restrict__ tab,
                                              unsigned short* __restrict__ q,
                                              unsigned short* __restrict__ k) {
  int bs = blockIdx.x;
  int bb = bs / NN, s = bs % NN;
  int lane = threadIdx.x & 63, wv = threadIdx.x >> 6;
  #pragma unroll
  for (int g = wv; g < 32; g += 4) {
    int i3 = g >> 4, h = g & 15;
    float val = bf2f(qkv[(size_t)bs * QKVN + g * 64 + lane]);
    float partner = __shfl_xor(val, 1);
    float2 cs = tab[(size_t)bs * 32 + (lane >> 1)];
    float out;
    if ((lane & 1) == 0) out = val * cs.x - partner * cs.y;      // t1*cos - t2*sin
    else                 out = partner * cs.y + val * cs.x;      // t1*sin + t2*cos
    if (i3 == 0) out *= 0.125f;
    unsigned short* dst = (i3 == 0) ? q : k;
    dst[((size_t)(bb * HH + h) * NN + s) * 64 + lane] = f2bf(out);
  }
}

// ---------------------------------------------------------------------------
// K5b: V transpose: qkvt[.][2048+h*64+dh] -> vT[bh][dh][s]  (bf16)
// ---------------------------------------------------------------------------
__global__ __launch_bounds__(256) void k_vtr(const unsigned short* __restrict__ qkvt,
                                             unsigned short* __restrict__ vT) {
  __shared__ unsigned short t[64][72];
  int s0 = blockIdx.x * 64, bh = blockIdx.y, bb = bh >> 4, h = bh & 15;
  int tid = threadIdx.x;
  int r = tid >> 2, c0 = (tid & 3) * 16;
  int cw = c0 ^ (((r >> 4) & 3) << 4);
  const unsigned short* src = qkvt + (size_t)(bb * NN + s0 + r) * QKVN + 2048 + h * 64 + c0;
  *(s16x8*)&t[r][cw]     = *(const s16x8*)src;
  *(s16x8*)&t[r][cw + 8] = *(const s16x8*)(src + 8);
  __syncthreads();
  int dh = tid >> 2, sc = (tid & 3) * 16;
  int col2 = dh ^ ((tid & 3) << 4);
  s16x8 o1, o2;
  #pragma unroll
  for (int i = 0; i < 8; ++i) {
    o1[i] = (short)t[sc + i][col2];
    o2[i] = (short)t[sc + 8 + i][col2];
  }
  unsigned short* dst = vT + ((size_t)bh * 64 + dh) * NN + s0 + sc;
  *(s16x8*)dst       = o1;
  *(s16x8*)(dst + 8) = o2;
}

// ---------------------------------------------------------------------------
// K6: flash attention. Paired q-tiles per block: 8 waves, waves 0-3 on the
// long tile (31-bx), waves 4-7 on the mirror short tile (bx); shared K/V
// double-buffer staging. Fixed-max softmax via cubic softcap (1 trans/elem).
// ---------------------------------------------------------------------------
__global__ __launch_bounds__(512) void k_attn(const unsigned short* __restrict__ q,
                                              const unsigned short* __restrict__ k,
                                              const unsigned short* __restrict__ vT,
                                              const int* __restrict__ mods,
                                              unsigned short* __restrict__ o) {
  __shared__ unsigned short Ks[2][64 * 64];
  __shared__ unsigned short Vs[2][64 * 64];
  __shared__ unsigned short Pw[8][16][72];
  int tid = threadIdx.x;
  int lane = tid & 63, wv = tid >> 6;
  int lo = lane & 15, hi = lane >> 4;

  int fid = blockIdx.y * gridDim.x + blockIdx.x;      // 0..511
  int nid = (fid & 7) * 64 + (fid >> 3);              // XCD-contiguous
  int bh = nid >> 4;
  int bx = nid & 15;
  int bb = bh >> 4;
  int q0A = (31 - bx) * 64;                           // long tile
  int q0B = bx * 64;                                  // mirror short tile
  int q0w = ((wv < 4) ? q0A : q0B) + (wv & 3) * 16;

  const unsigned short* qb = q + (size_t)bh * NN * 64;
  const unsigned short* kb = k + (size_t)bh * NN * 64;
  const unsigned short* vb = vT + (size_t)bh * 64 * NN;

  s16x8 qf[2];
  {
    int qrow = q0w + lo;
    #pragma unroll
    for (int ks = 0; ks < 2; ++ks)
      qf[ks] = *(const s16x8*)&qb[(size_t)qrow * 64 + ks * 32 + hi * 8];
  }

  int off_[MMOD], end_[MMOD];
  #pragma unroll
  for (int m = 0; m < MMOD; ++m) {
    off_[m] = mods[(bb * MMOD + m) * 3 + 1];
    end_[m] = off_[m] + mods[(bb * MMOD + m) * 3 + 2];
  }
  int limit[4];
  #pragma unroll
  for (int j = 0; j < 4; ++j) {
    int r = q0w + hi * 4 + j;
    int L = r + 1;
    #pragma unroll
    for (int m = 0; m < MMOD; ++m)
      if (off_[m] <= r && end_[m] > L) L = end_[m];
    limit[j] = L;
  }
  int minlim, kvmax_w;
  {
    int L = q0w + 1;
    #pragma unroll
    for (int m = 0; m < MMOD; ++m)
      if (off_[m] <= q0w && end_[m] > L) L = end_[m];
    minlim = L;
    int r = q0w + 15;
    int L2 = r + 1;
    #pragma unroll
    for (int m = 0; m < MMOD; ++m)
      if (off_[m] <= r && end_[m] > L2) L2 = end_[m];
    kvmax_w = L2;
  }
  int nt;
  {
    int ra = q0A + 63;
    int LA = ra + 1;
    #pragma unroll
    for (int m = 0; m < MMOD; ++m)
      if (off_[m] <= ra && end_[m] > LA) LA = end_[m];
    int rb2 = q0B + 63;
    int LB = rb2 + 1;
    #pragma unroll
    for (int m = 0; m < MMOD; ++m)
      if (off_[m] <= rb2 && end_[m] > LB) LB = end_[m];
    int Lblk = (LA > LB) ? LA : LB;
    nt = (Lblk + 63) >> 6;
  }

  // 512 threads stage one 16B chunk each of K and V per tile.
  #define STAGE_KV(B, KV0) do { \
    int r_ = tid >> 3; \
    int cs_ = (lane & 7) ^ ((lane >> 3) & 7); \
    const unsigned short* gK_ = kb + (size_t)((KV0) + r_) * 64 + cs_ * 8; \
    ASYNC_LDS16(gK_, &Ks[B][wv * 512]); \
    const unsigned short* gV_ = vb + (size_t)r_ * NN + (KV0) + cs_ * 8; \
    ASYNC_LDS16(gV_, &Vs[B][wv * 512]); \
  } while (0)

  float lrunp[4] = {0.f, 0.f, 0.f, 0.f};
  f32x4 accO[4] = {};

  STAGE_KV(0, 0);
  __syncthreads();
  int buf = 0;
  for (int t = 0; t < nt; ++t) {
    if (t + 1 < nt) STAGE_KV(buf ^ 1, (t + 1) << 6);
    int kv0 = t << 6;
    if (kv0 < kvmax_w) {
      // QK^T from swizzled LDS
      f32x4 sv[4];
      #pragma unroll
      for (int cb = 0; cb < 4; ++cb) {
        int krow = cb * 16 + lo;
        int c0 = (hi) ^ (krow & 7);
        int c1 = (4 + hi) ^ (krow & 7);
        s16x8 kf0 = *(const s16x8*)&Ks[buf][krow * 64 + c0 * 8];
        s16x8 kf1 = *(const s16x8*)&Ks[buf][krow * 64 + c1 * 8];
        f32x4 z = {};
        z = __builtin_amdgcn_mfma_f32_16x16x32_bf16(qf[0], kf0, z, 0, 0, 0);
        z = __builtin_amdgcn_mfma_f32_16x16x32_bf16(qf[1], kf1, z, 0, 0, 0);
        sv[cb] = z;
      }

      // p = exp(50 tanh(s/50)) ~= exp(s - s^3/7500); e^-50 shift cancels.
      if (kv0 + 64 <= minlim) {
        #pragma unroll
        for (int cb = 0; cb < 4; ++cb)
          #pragma unroll
          for (int j = 0; j < 4; ++j) {
            float s = sv[cb][j];
            float t2 = s * s;
            float u = __builtin_fmaf(t2, -1.3333333e-4f, 1.0f);
            float cap = __builtin_amdgcn_fmed3f(s * u, -50.f, 50.f);
            float p = __expf(cap);
            lrunp[j] += p;
            Pw[wv][hi * 4 + j][cb * 16 + lo] =
                (unsigned short)(__float_as_uint(p) >> 16);
          }
      } else {
        #pragma unroll
        for (int cb = 0; cb < 4; ++cb) {
          int col = kv0 + cb * 16 + lo;
          #pragma unroll
          for (int j = 0; j < 4; ++j) {
            float s = sv[cb][j];
            float t2 = s * s;
            float u = __builtin_fmaf(t2, -1.3333333e-4f, 1.0f);
            float cap = __builtin_amdgcn_fmed3f(s * u, -50.f, 50.f);
            float p = __expf(cap);
            if (col >= limit[j]) p = 0.f;
            lrunp[j] += p;
            Pw[wv][hi * 4 + j][cb * 16 + lo] =
                (unsigned short)(__float_as_uint(p) >> 16);
          }
        }
      }

      // PV from swizzled LDS
      #pragma unroll
      for (int ks = 0; ks < 2; ++ks) {
        s16x8 pa = *(const s16x8*)&Pw[wv][lo][ks * 32 + hi * 8];
        #pragma unroll
        for (int cb = 0; cb < 4; ++cb) {
          int vrow = cb * 16 + lo;
          int vc = (ks * 4 + hi) ^ (vrow & 7);
          s16x8 vf = *(const s16x8*)&Vs[buf][vrow * 64 + vc * 8];
          accO[cb] = __builtin_amdgcn_mfma_f32_16x16x32_bf16(pa, vf, accO[cb], 0, 0, 0);
        }
      }
    }
    __syncthreads();
    buf ^= 1;
  }

  #pragma unroll
  for (int o2 = 1; o2 < 16; o2 <<= 1)
    #pragma unroll
    for (int j = 0; j < 4; ++j) lrunp[j] += __shfl_xor(lrunp[j], o2);

  int h = bh & 15;
  float rl[4];
  #pragma unroll
  for (int j = 0; j < 4; ++j) rl[j] = __builtin_amdgcn_rcpf(lrunp[j]);
  #pragma unroll
  for (int cb = 0; cb < 4; ++cb)
    #pragma unroll
    for (int j = 0; j < 4; ++j) {
      int r = q0w + hi * 4 + j;
      float val = accO[cb][j] * rl[j];
      o[((size_t)(bb * NN) + r) * (HH * DHD) + h * 64 + cb * 16 + lo] = f2bf(val);
    }
}

// ---------------------------------------------------------------------------
extern "C" void kernel_launch(void* const* d_in, const int* in_sizes, int n_in,
                              void* d_out, int out_size, void* d_ws, size_t ws_size,
                              hipStream_t stream) {
  (void)in_sizes; (void)n_in; (void)out_size; (void)ws_size;
  const float* x      = (const float*)d_in[0];
  const float* tokens = (const float*)d_in[1];
  const float* gamma  = (const float*)d_in[2];
  const float* w_qkv  = (const float*)d_in[3];
  const float* w_out  = (const float*)d_in[4];
  const int*   mods   = (const int*)d_in[5];

  char* ws = (char*)d_ws;
  unsigned short* xn    = (unsigned short*)(ws + 0);           //  8 MB
  unsigned short* wqkvT = (unsigned short*)(ws + 8388608);     //  6 MB
  unsigned short* woutT = (unsigned short*)(ws + 14680064);    //  2 MB
  unsigned short* qkvt  = (unsigned short*)(ws + 16777216);    // 24 MB
  unsigned short* qd    = (unsigned short*)(ws + 41943040);    //  8 MB
  unsigned short* kd    = (unsigned short*)(ws + 50331648);    //  8 MB
  unsigned short* vTd   = (unsigned short*)(ws + 58720256);    //  8 MB
  unsigned short* attno = (unsigned short*)(ws + 67108864);    //  8 MB
  int*            pos   = (int*)(ws + 75497472);               // 16 KB
  float2*         tab   = (float2*)(ws + 75513856);            //  1 MB

  k_prep<<<BNROWS, 256, 0, stream>>>(x, tokens, gamma, mods, xn);
  k_pos<<<BB, 64, 0, stream>>>(mods, pos);
  k_tab<<<(BB * NN * 32) / 256, 256, 0, stream>>>(pos, tab);
  k_tr<<<dim3(QKVN / 32, DD / 32), dim3(32, 8), 0, stream>>>(w_qkv, wqkvT, DD, QKVN);
  k_tr<<<dim3((HH * DHD) / 32, DD / 32), dim3(32, 8), 0, stream>>>(w_out, woutT, HH * DHD, DD);
  k_gemm<false><<<dim3(QKVN / 128, BNROWS / 128), 256, 0, stream>>>(xn, wqkvT, (void*)qkvt, BNROWS, QKVN, DD);
  k_rope<<<BNROWS, 256, 0, stream>>>(qkvt, tab, qd, kd);
  k_vtr<<<dim3(NN / 64, BB * HH), 256, 0, stream>>>(qkvt, vTd);
  k_attn<<<dim3(16, BB * HH), 512, 0, stream>>>(qd, kd, vTd, mods, attno);
  k_gemm<true><<<dim3(DD / 128, BNROWS / 128), 256, 0, stream>>>(attno, woutT, d_out, BNROWS, DD, DD);
}